// Round 5
// baseline (515.822 us; speedup 1.0000x reference)
//
#include <hip/hip_runtime.h>

typedef short short8 __attribute__((ext_vector_type(8)));
typedef float f32x4 __attribute__((ext_vector_type(4)));

__device__ __forceinline__ f32x4 mfma16(short8 a, short8 b, f32x4 c) {
    return __builtin_amdgcn_mfma_f32_16x16x32_bf16(a, b, c, 0, 0, 0);
}
__device__ __forceinline__ short f2bs(float f) {
    __bf16 h = (__bf16)f;
    return __builtin_bit_cast(short, h);
}
__device__ __forceinline__ void gld_lds16(const void* g, void* l) {
    __builtin_amdgcn_global_load_lds(
        (const __attribute__((address_space(1))) void*)g,
        (__attribute__((address_space(3))) void*)l, 16, 0, 0);
}

// ---------------------------------------------------------------------------
// fp32 -> bf16 bulk convert (8 elems/thread)
// ---------------------------------------------------------------------------
__global__ __launch_bounds__(256) void cvt_b16(const float* __restrict__ in,
                                               short* __restrict__ out) {
    const size_t i = ((size_t)blockIdx.x * 256 + threadIdx.x) * 8;
    const float4 v0 = *(const float4*)(in + i);
    const float4 v1 = *(const float4*)(in + i + 4);
    short8 s;
    s[0] = f2bs(v0.x); s[1] = f2bs(v0.y); s[2] = f2bs(v0.z); s[3] = f2bs(v0.w);
    s[4] = f2bs(v1.x); s[5] = f2bs(v1.y); s[6] = f2bs(v1.z); s[7] = f2bs(v1.w);
    *(short8*)(out + i) = s;
}

// ---------------------------------------------------------------------------
// MFMA GEMM-BT: C[r][n] = sum_k A[r][k]*W[n][k] + bias[n]
// A bf16 [8192][768] staged via global_load_lds_dwordx4 (linear dest,
// pre-swizzled source); W fp32 register-staged with the same XOR swizzle.
// 128x128 tile, BK=64, 12 K-steps, 32 MFMA per barrier pair.
// mode 0: C bf16 row-major; mode 1: C bf16 Vt[b][768][1024]; mode 2: C fp32.
// ---------------------------------------------------------------------------
__global__ __launch_bounds__(256) void gemm_mfma(const short* __restrict__ A,
                                                 const float* __restrict__ W,
                                                 const float* __restrict__ bias,
                                                 void* __restrict__ Cv,
                                                 int mode) {
    __shared__ short sA[128][64];
    __shared__ short sW[128][64];

    const int tid = threadIdx.x;
    const int wave = tid >> 6, lane = tid & 63;
    const int quad = lane >> 4, l16 = lane & 15;
    const int n0 = blockIdx.x * 128;
    const int r0 = blockIdx.y * 128;
    const int wm = (wave & 1) * 64;
    const int wn = (wave >> 1) * 64;

    const int lrow   = lane >> 3;                 // 0..7 (row within 8-row group)
    const int lchunk = (lane & 7) ^ lrow;         // pre-swizzled source chunk
    const short* Abase =
        A + (size_t)(r0 + wave * 32 + lrow) * 768 + lchunk * 8;

    const int wrow = tid >> 1;
    const int wseg = tid & 1;
    const float* Wbase = W + (size_t)(n0 + wrow) * 768 + wseg * 32;
    const int wsw = wrow & 7;                     // row swizzle key

    f32x4 acc[4][4];
#pragma unroll
    for (int mt = 0; mt < 4; ++mt)
#pragma unroll
        for (int nt = 0; nt < 4; ++nt) acc[mt][nt] = (f32x4){0.f, 0.f, 0.f, 0.f};

    for (int k0 = 0; k0 < 768; k0 += 64) {
        float4 wv[8];
#pragma unroll
        for (int j = 0; j < 8; ++j)
            wv[j] = *(const float4*)(Wbase + k0 + j * 4);

        __syncthreads();  // all waves done reading previous tile

#pragma unroll
        for (int i = 0; i < 4; ++i)
            gld_lds16(Abase + k0 + (size_t)i * 8 * 768,
                      &sA[(wave * 4 + i) * 8][0]);

#pragma unroll
        for (int c = 0; c < 4; ++c) {
            const float4 a = wv[2 * c], b = wv[2 * c + 1];
            short8 p;
            p[0] = f2bs(a.x); p[1] = f2bs(a.y); p[2] = f2bs(a.z); p[3] = f2bs(a.w);
            p[4] = f2bs(b.x); p[5] = f2bs(b.y); p[6] = f2bs(b.z); p[7] = f2bs(b.w);
            *(short8*)&sW[wrow][((wseg * 4 + c) ^ wsw) * 8] = p;
        }

        __syncthreads();  // compiler drains vmcnt(0)+lgkmcnt(0) here

#pragma unroll
        for (int ks = 0; ks < 2; ++ks) {
            short8 af[4], bf[4];
#pragma unroll
            for (int mt = 0; mt < 4; ++mt)
                af[mt] = *(const short8*)
                    &sA[wm + mt * 16 + l16][((ks * 4 + quad) ^ (l16 & 7)) * 8];
#pragma unroll
            for (int nt = 0; nt < 4; ++nt)
                bf[nt] = *(const short8*)
                    &sW[wn + nt * 16 + l16][((ks * 4 + quad) ^ (l16 & 7)) * 8];
#pragma unroll
            for (int mt = 0; mt < 4; ++mt)
#pragma unroll
                for (int nt = 0; nt < 4; ++nt)
                    acc[mt][nt] = mfma16(af[mt], bf[nt], acc[mt][nt]);
        }
    }

    short* Cs = (short*)Cv;
    float* Cf = (float*)Cv;
#pragma unroll
    for (int nt = 0; nt < 4; ++nt) {
        const int n = n0 + wn + nt * 16 + l16;
        const float bv = bias[n];
#pragma unroll
        for (int mt = 0; mt < 4; ++mt) {
#pragma unroll
            for (int rr = 0; rr < 4; ++rr) {
                const int row = r0 + wm + mt * 16 + quad * 4 + rr;
                const float val = acc[mt][nt][rr] + bv;
                if (mode == 0) {
                    Cs[(size_t)row * 768 + n] = f2bs(val);
                } else if (mode == 1) {
                    Cs[((size_t)(row >> 10) * 768 + n) * 1024 + (row & 1023)] = f2bs(val);
                } else {
                    Cf[(size_t)row * 768 + n] = val;
                }
            }
        }
    }
}

// ---------------------------------------------------------------------------
// Flash attention, no-max softmax. Round-4: grid (8h, 16mt, 8b) -> h on x
// puts all blocks sharing one (h,b) K/V panel on ONE XCD (linear%8 = h);
// 64-row m-tiles (1 fragment/wave) double block count to 1024 (4/CU) and
// cut per-wave state ~36 VGPR. Inner loop instruction-identical to the
// proven version, minus the mf dimension.
// ---------------------------------------------------------------------------
__global__ __launch_bounds__(256) void flash_att(const short* __restrict__ Q,
                                                 const short* __restrict__ K,
                                                 const short* __restrict__ Vt,
                                                 short* __restrict__ att,
                                                 float* __restrict__ linv) {
    const int h  = blockIdx.x;   // XCD selector
    const int mt = blockIdx.y;   // 0..15, 64-row tile
    const int b  = blockIdx.z;
    const int tid  = threadIdx.x;
    const int wave = tid >> 6;
    const int lane = tid & 63;
    const int quad = lane >> 4;
    const int l16  = lane & 15;

    __shared__ short Pl[4][16][40];  // 4 waves x 16 rows

    const int m0 = mt * 64 + wave * 16;
    const size_t brow = (size_t)b * 1024;

    short8 aq[3];
    {
        const short* qbase = Q + (brow + m0 + l16) * 768 + h * 96 + quad * 8;
        aq[0] = *(const short8*)(qbase);
        aq[1] = *(const short8*)(qbase + 32);
        aq[2] = *(const short8*)(qbase + 64);
    }

    f32x4 o[6];
#pragma unroll
    for (int nt = 0; nt < 6; ++nt) o[nt] = (f32x4){0.f, 0.f, 0.f, 0.f};
    float li[4] = {};

    const float scale = 0.1020620726159657f;  // 1/sqrt(96)
    const short* kbase = K + brow * 768 + h * 96 + quad * 8;
    const short* vtb = Vt + ((size_t)b * 768 + h * 96) * 1024;

    short8 kcur[6], knxt[6];
    {
        const short* k0p = kbase + (size_t)l16 * 768;
        const short* k1p = k0p + 16 * 768;
        kcur[0] = *(const short8*)(k0p);
        kcur[1] = *(const short8*)(k0p + 32);
        kcur[2] = *(const short8*)(k0p + 64);
        kcur[3] = *(const short8*)(k1p);
        kcur[4] = *(const short8*)(k1p + 32);
        kcur[5] = *(const short8*)(k1p + 64);
    }

    for (int p0 = 0; p0 < 1024; p0 += 32) {
        // Vt for THIS iteration (consumed last -> latency hidden behind S/exp)
        short8 vt[6];
#pragma unroll
        for (int nt = 0; nt < 6; ++nt)
            vt[nt] = *(const short8*)(vtb + (size_t)(nt * 16 + l16) * 1024 +
                                      p0 + quad * 8);
        // K prefetch for next iteration (stays in flight across PV)
        {
            const int pn = (p0 + 32) & 1023;
            const short* k0p = kbase + (size_t)(pn + l16) * 768;
            const short* k1p = k0p + 16 * 768;
            knxt[0] = *(const short8*)(k0p);
            knxt[1] = *(const short8*)(k0p + 32);
            knxt[2] = *(const short8*)(k0p + 64);
            knxt[3] = *(const short8*)(k1p);
            knxt[4] = *(const short8*)(k1p + 32);
            knxt[5] = *(const short8*)(k1p + 64);
        }

        float e0[4], e1[4];
        {
            f32x4 s0 = (f32x4){0.f, 0.f, 0.f, 0.f};
            f32x4 s1 = (f32x4){0.f, 0.f, 0.f, 0.f};
            s0 = mfma16(aq[0], kcur[0], s0);
            s0 = mfma16(aq[1], kcur[1], s0);
            s0 = mfma16(aq[2], kcur[2], s0);
            s1 = mfma16(aq[0], kcur[3], s1);
            s1 = mfma16(aq[1], kcur[4], s1);
            s1 = mfma16(aq[2], kcur[5], s1);
#pragma unroll
            for (int r = 0; r < 4; ++r) {
                e0[r] = __expf(s0[r] * scale);
                e1[r] = __expf(s1[r] * scale);
                li[r] += e0[r] + e1[r];
            }
        }

        // P (C-layout) -> LDS -> A-layout; lgkm-only wait (vmcnt stays open)
#pragma unroll
        for (int r = 0; r < 4; ++r) {
            Pl[wave][quad * 4 + r][l16]      = f2bs(e0[r]);
            Pl[wave][quad * 4 + r][l16 + 16] = f2bs(e1[r]);
        }
        __builtin_amdgcn_s_waitcnt(0xc07f);  // lgkmcnt(0) only
        {
            const short4 plo = *(const short4*)&Pl[wave][l16][quad * 8];
            const short4 phi = *(const short4*)&Pl[wave][l16][quad * 8 + 4];
            const short8 ap = (short8){plo.x, plo.y, plo.z, plo.w,
                                       phi.x, phi.y, phi.z, phi.w};
#pragma unroll
            for (int nt = 0; nt < 6; ++nt) o[nt] = mfma16(ap, vt[nt], o[nt]);
        }

#pragma unroll
        for (int j = 0; j < 6; ++j) kcur[j] = knxt[j];
    }

    {
        float inv[4];
#pragma unroll
        for (int r = 0; r < 4; ++r) {
#pragma unroll
            for (int off = 1; off < 16; off <<= 1)
                li[r] += __shfl_xor(li[r], off, 16);
            inv[r] = 1.0f / li[r];
        }
#pragma unroll
        for (int nt = 0; nt < 6; ++nt)
#pragma unroll
            for (int r = 0; r < 4; ++r)
                att[(brow + m0 + quad * 4 + r) * 768 + h * 96 + nt * 16 + l16] =
                    f2bs(o[nt][r] * inv[r]);
        if (l16 == 0) {
#pragma unroll
            for (int r = 0; r < 4; ++r)
                linv[(((size_t)b * 8 + h) << 10) + m0 + quad * 4 + r] = inv[r];
        }
    }
}

// ---------------------------------------------------------------------------
// Head-averaged attention map, gemm-pattern 2-barrier DMA structure (round-3,
// proven). Grid (8 pt, 8 mt, 8 b) = 512 blocks, 4 waves, each wave 64m x 64p.
// ---------------------------------------------------------------------------
__global__ __launch_bounds__(256) void attn_avg5(const short* __restrict__ Q,
                                                 const short* __restrict__ K,
                                                 const float* __restrict__ linv,
                                                 float* __restrict__ avg) {
    __shared__ short sQ[12][128][8];  // 24 KB
    __shared__ short sK[12][128][8];  // 24 KB

    const int pt = blockIdx.x;
    const int mt = blockIdx.y;
    const int b  = blockIdx.z;
    const int tid  = threadIdx.x;
    const int wave = tid >> 6;
    const int lane = tid & 63;
    const int quad = lane >> 4;
    const int l16  = lane & 15;

    const int m0 = mt * 128;
    const int p0 = pt * 128;
    const size_t brow = (size_t)b * 1024;
    const int wm = (wave & 1) * 64;
    const int wn = (wave >> 1) * 64;
    const float scale2 = 0.14724445f;  // (1/sqrt(96)) * log2(e)

    const short* Qsrc = Q + (brow + m0 + lane) * 768;
    const short* Ksrc = K + (brow + p0 + lane) * 768;
    const float* Lb_  = linv + (((size_t)b * 8) << 10) + m0 + wm + quad * 4;

    f32x4 acc[4][4];
#pragma unroll
    for (int x = 0; x < 4; ++x)
#pragma unroll
        for (int y = 0; y < 4; ++y) acc[x][y] = (f32x4){0.f, 0.f, 0.f, 0.f};

#pragma unroll 1
    for (int h = 0; h < 8; ++h) {
        __syncthreads();  // previous step's fragment reads complete

#pragma unroll
        for (int i = 0; i < 6; ++i) {
            const int j = wave * 6 + i;
            const int c = j >> 1, half = j & 1;
            gld_lds16(Qsrc + (size_t)(half * 64) * 768 + h * 96 + c * 8,
                      &sQ[c][half * 64][0]);
            gld_lds16(Ksrc + (size_t)(half * 64) * 768 + h * 96 + c * 8,
                      &sK[c][half * 64][0]);
        }

        f32x4 il[4];
#pragma unroll
        for (int x = 0; x < 4; ++x)
            il[x] = 0.125f * *(const f32x4*)(Lb_ + ((size_t)h << 10) + x * 16);

        __syncthreads();  // drains vmcnt: LDS tiles ready

        short8 af[4][3], bf[4][3];
#pragma unroll
        for (int x = 0; x < 4; ++x)
#pragma unroll
            for (int kc = 0; kc < 3; ++kc) {
                af[x][kc] = *(const short8*)&sQ[kc * 4 + quad][wm + x * 16 + l16][0];
                bf[x][kc] = *(const short8*)&sK[kc * 4 + quad][wn + x * 16 + l16][0];
            }

#pragma unroll
        for (int x = 0; x < 4; ++x)
#pragma unroll
            for (int y = 0; y < 4; ++y) {
                f32x4 s = (f32x4){0.f, 0.f, 0.f, 0.f};
                s = mfma16(af[x][0], bf[y][0], s);
                s = mfma16(af[x][1], bf[y][1], s);
                s = mfma16(af[x][2], bf[y][2], s);
#pragma unroll
                for (int r = 0; r < 4; ++r)
                    acc[x][y][r] += __builtin_exp2f(s[r] * scale2) * il[x][r];
            }
    }

#pragma unroll
    for (int x = 0; x < 4; ++x)
#pragma unroll
        for (int y = 0; y < 4; ++y)
#pragma unroll
            for (int r = 0; r < 4; ++r)
                avg[(brow + m0 + wm + x * 16 + quad * 4 + r) * 1024 +
                    p0 + wn + y * 16 + l16] = acc[x][y][r];
}

extern "C" void kernel_launch(void* const* d_in, const int* in_sizes, int n_in,
                              void* d_out, int out_size, void* d_ws, size_t ws_size,
                              hipStream_t stream) {
    (void)in_sizes; (void)n_in; (void)out_size; (void)d_ws; (void)ws_size;

    float* mam = (float*)d_in[0];
    float* pat = (float*)d_in[1];
    const float* qw = (const float*)d_in[2];
    const float* qb = (const float*)d_in[3];
    const float* kw = (const float*)d_in[4];
    const float* kb = (const float*)d_in[5];
    const float* vw = (const float*)d_in[6];
    const float* vb = (const float*)d_in[7];
    const float* ow = (const float*)d_in[8];
    const float* ob = (const float*)d_in[9];

    const size_t NTOK = (size_t)8 * 1024 * 768;
    float* out_att = (float*)d_out;
    float* out_avg = out_att + NTOK;

    short* Am = (short*)d_out;           // bf16 mammo  @ out_att head (dead after Q-proj)
    short* Ap = (short*)out_avg;         // bf16 patho  @ out_avg head (dead after V-proj)
    short* Qb = (short*)mam;             // bf16 Q      @ mammo[0:NTOK]
    short* Kb = Qb + NTOK;               // bf16 K      @ mammo[NTOK:2*NTOK]
    short* Vt = (short*)pat;             // bf16 Vt     @ patho[0:NTOK]
    short* Ab = Vt + NTOK;               // bf16 att    @ patho[NTOK:2*NTOK]
    float* LV = (float*)(Am + NTOK);     // 1/l (256KB) @ out_att tail (dead before O-proj)

    dim3 bb(256), gg(6, 64);
    cvt_b16<<<3072, bb, 0, stream>>>(mam, Am);
    cvt_b16<<<3072, bb, 0, stream>>>(pat, Ap);
    gemm_mfma<<<gg, bb, 0, stream>>>(Am, qw, qb, Qb, 0);
    gemm_mfma<<<gg, bb, 0, stream>>>(Ap, kw, kb, Kb, 0);
    gemm_mfma<<<gg, bb, 0, stream>>>(Ap, vw, vb, Vt, 1);

    flash_att<<<dim3(8, 16, 8), bb, 0, stream>>>(Qb, Kb, Vt, Ab, LV);
    attn_avg5<<<dim3(8, 8, 8), bb, 0, stream>>>(Qb, Kb, LV, out_avg);

    gemm_mfma<<<gg, bb, 0, stream>>>(Ab, ow, ob, out_att, 2);
}

// Round 7
// 390.478 us; speedup vs baseline: 1.3210x; 1.3210x over previous
//
#include <hip/hip_runtime.h>

typedef short short8 __attribute__((ext_vector_type(8)));
typedef float f32x4 __attribute__((ext_vector_type(4)));

__device__ __forceinline__ f32x4 mfma16(short8 a, short8 b, f32x4 c) {
    return __builtin_amdgcn_mfma_f32_16x16x32_bf16(a, b, c, 0, 0, 0);
}
__device__ __forceinline__ short f2bs(float f) {
    __bf16 h = (__bf16)f;
    return __builtin_bit_cast(short, h);
}
__device__ __forceinline__ void gld_lds16(const void* g, void* l) {
    __builtin_amdgcn_global_load_lds(
        (const __attribute__((address_space(1))) void*)g,
        (__attribute__((address_space(3))) void*)l, 16, 0, 0);
}

// ---------------------------------------------------------------------------
// fp32 -> bf16 bulk convert (8 elems/thread)
// ---------------------------------------------------------------------------
__global__ __launch_bounds__(256) void cvt_b16(const float* __restrict__ in,
                                               short* __restrict__ out) {
    const size_t i = ((size_t)blockIdx.x * 256 + threadIdx.x) * 8;
    const float4 v0 = *(const float4*)(in + i);
    const float4 v1 = *(const float4*)(in + i + 4);
    short8 s;
    s[0] = f2bs(v0.x); s[1] = f2bs(v0.y); s[2] = f2bs(v0.z); s[3] = f2bs(v0.w);
    s[4] = f2bs(v1.x); s[5] = f2bs(v1.y); s[6] = f2bs(v1.z); s[7] = f2bs(v1.w);
    *(short8*)(out + i) = s;
}

// ---------------------------------------------------------------------------
// MFMA GEMM-BT: C[r][n] = sum_k A[r][k]*W[n][k] + bias[n]
// (proven, unchanged)
// ---------------------------------------------------------------------------
__global__ __launch_bounds__(256) void gemm_mfma(const short* __restrict__ A,
                                                 const float* __restrict__ W,
                                                 const float* __restrict__ bias,
                                                 void* __restrict__ Cv,
                                                 int mode) {
    __shared__ short sA[128][64];
    __shared__ short sW[128][64];

    const int tid = threadIdx.x;
    const int wave = tid >> 6, lane = tid & 63;
    const int quad = lane >> 4, l16 = lane & 15;
    const int n0 = blockIdx.x * 128;
    const int r0 = blockIdx.y * 128;
    const int wm = (wave & 1) * 64;
    const int wn = (wave >> 1) * 64;

    const int lrow   = lane >> 3;
    const int lchunk = (lane & 7) ^ lrow;
    const short* Abase =
        A + (size_t)(r0 + wave * 32 + lrow) * 768 + lchunk * 8;

    const int wrow = tid >> 1;
    const int wseg = tid & 1;
    const float* Wbase = W + (size_t)(n0 + wrow) * 768 + wseg * 32;
    const int wsw = wrow & 7;

    f32x4 acc[4][4];
#pragma unroll
    for (int mt = 0; mt < 4; ++mt)
#pragma unroll
        for (int nt = 0; nt < 4; ++nt) acc[mt][nt] = (f32x4){0.f, 0.f, 0.f, 0.f};

    for (int k0 = 0; k0 < 768; k0 += 64) {
        float4 wv[8];
#pragma unroll
        for (int j = 0; j < 8; ++j)
            wv[j] = *(const float4*)(Wbase + k0 + j * 4);

        __syncthreads();

#pragma unroll
        for (int i = 0; i < 4; ++i)
            gld_lds16(Abase + k0 + (size_t)i * 8 * 768,
                      &sA[(wave * 4 + i) * 8][0]);

#pragma unroll
        for (int c = 0; c < 4; ++c) {
            const float4 a = wv[2 * c], b = wv[2 * c + 1];
            short8 p;
            p[0] = f2bs(a.x); p[1] = f2bs(a.y); p[2] = f2bs(a.z); p[3] = f2bs(a.w);
            p[4] = f2bs(b.x); p[5] = f2bs(b.y); p[6] = f2bs(b.z); p[7] = f2bs(b.w);
            *(short8*)&sW[wrow][((wseg * 4 + c) ^ wsw) * 8] = p;
        }

        __syncthreads();

#pragma unroll
        for (int ks = 0; ks < 2; ++ks) {
            short8 af[4], bf[4];
#pragma unroll
            for (int mt = 0; mt < 4; ++mt)
                af[mt] = *(const short8*)
                    &sA[wm + mt * 16 + l16][((ks * 4 + quad) ^ (l16 & 7)) * 8];
#pragma unroll
            for (int nt = 0; nt < 4; ++nt)
                bf[nt] = *(const short8*)
                    &sW[wn + nt * 16 + l16][((ks * 4 + quad) ^ (l16 & 7)) * 8];
#pragma unroll
            for (int mt = 0; mt < 4; ++mt)
#pragma unroll
                for (int nt = 0; nt < 4; ++nt)
                    acc[mt][nt] = mfma16(af[mt], bf[nt], acc[mt][nt]);
        }
    }

    short* Cs = (short*)Cv;
    float* Cf = (float*)Cv;
#pragma unroll
    for (int nt = 0; nt < 4; ++nt) {
        const int n = n0 + wn + nt * 16 + l16;
        const float bv = bias[n];
#pragma unroll
        for (int mt = 0; mt < 4; ++mt) {
#pragma unroll
            for (int rr = 0; rr < 4; ++rr) {
                const int row = r0 + wm + mt * 16 + quad * 4 + rr;
                const float val = acc[mt][nt][rr] + bv;
                if (mode == 0) {
                    Cs[(size_t)row * 768 + n] = f2bs(val);
                } else if (mode == 1) {
                    Cs[((size_t)(row >> 10) * 768 + n) * 1024 + (row & 1023)] = f2bs(val);
                } else {
                    Cf[(size_t)row * 768 + n] = val;
                }
            }
        }
    }
}

// ---------------------------------------------------------------------------
// Flash attention, round-6: round-5 structure with the V-read row-stride
// bug fixed (sV row stride is 64 shorts -> PV read offset nt*1024, was
// nt*2048 which read wrong rows / past the array).
// K/Vt staged through LDS with the gemm-proven 2-barrier global_load_lds
// structure. Grid (8h, 8mt, 8b): h on x keeps XCD L2 locality (verified).
// 128 m-rows/block (4 waves x 32 rows, mf=2), PBLK=64 -> 16 steps of
// {sync, 7 DMA, sync, 24 QK MFMA, exp, P-LDS-transpose, 24 PV MFMA}.
//   sK[64][16][8]: p-row major, content chunk g at pos g^(row&7), 12 of 16
//                  chunks used (src clamped; pad slots never read);
//   sV[96][8][8]:  d-row major, chunk g at pos g^(row&7);
//   Pl[4][32][76]: P transpose, pad-76 stride.
// ---------------------------------------------------------------------------
__global__ __launch_bounds__(256) void flash_att(const short* __restrict__ Q,
                                                 const short* __restrict__ K,
                                                 const short* __restrict__ Vt,
                                                 short* __restrict__ att,
                                                 float* __restrict__ linv) {
    __shared__ short sK[64][16][8];   // 16 KB
    __shared__ short sV[96][8][8];    // 12 KB
    __shared__ short Pl[4][32][76];   // 19 KB

    const int h  = blockIdx.x;   // XCD selector
    const int mt = blockIdx.y;
    const int b  = blockIdx.z;
    const int tid  = threadIdx.x;
    const int wave = tid >> 6;
    const int lane = tid & 63;
    const int quad = lane >> 4;
    const int l16  = lane & 15;

    const int m0 = mt * 128 + wave * 32;
    const size_t brow = (size_t)b * 1024;
    const float scale = 0.1020620726159657f;  // 1/sqrt(96)

    // Q fragments (once per kernel)
    short8 aq[2][3];
#pragma unroll
    for (int mf = 0; mf < 2; ++mf) {
        const short* qbase = Q + (brow + m0 + mf * 16 + l16) * 768 + h * 96 + quad * 8;
        aq[mf][0] = *(const short8*)(qbase);
        aq[mf][1] = *(const short8*)(qbase + 32);
        aq[mf][2] = *(const short8*)(qbase + 64);
    }

    // --- DMA source pointers (per-lane constants, advanced per step) ---
    // K: 1024 slots, slot = i*256+tid; row=slot>>4, chunkpos=slot&15,
    //    content chunk g = chunkpos ^ (row&7), clamped to 11 (pad slots).
    const short* kp_[4];
#pragma unroll
    for (int i = 0; i < 4; ++i) {
        const int slot = i * 256 + tid;
        const int row = slot >> 4;
        int g = (slot & 15) ^ (row & 7);
        if (g > 11) g = 11;
        kp_[i] = K + (brow + row) * 768 + h * 96 + g * 8;
    }
    // V: 768 slots, row=slot>>3 (d), chunkpos=slot&7, g = chunkpos^(row&7).
    const short* vp_[3];
#pragma unroll
    for (int i = 0; i < 3; ++i) {
        const int slot = i * 256 + tid;
        const int row = slot >> 3;
        const int g = (slot & 7) ^ (row & 7);
        vp_[i] = Vt + ((size_t)b * 768 + h * 96 + row) * 1024 + g * 8;
    }

    // --- per-lane LDS read bases (short offsets) ---
    int kB[3], vB[2];
#pragma unroll
    for (int kc = 0; kc < 3; ++kc)
        kB[kc] = l16 * 128 + (((kc * 4 + quad) ^ (l16 & 7)) * 8);
#pragma unroll
    for (int kv = 0; kv < 2; ++kv)
        vB[kv] = l16 * 64 + (((kv * 4 + quad) ^ (l16 & 7)) * 8);

    f32x4 o[2][6];
#pragma unroll
    for (int mf = 0; mf < 2; ++mf)
#pragma unroll
        for (int nt = 0; nt < 6; ++nt) o[mf][nt] = (f32x4){0.f, 0.f, 0.f, 0.f};
    float li[2][4] = {};

    for (int p0 = 0; p0 < 1024; p0 += 64) {
        __syncthreads();  // all waves done reading previous tiles

#pragma unroll
        for (int i = 0; i < 4; ++i) {
            gld_lds16(kp_[i], (short*)sK + (i * 256 + wave * 64) * 8);
            kp_[i] += 64 * 768;
        }
#pragma unroll
        for (int i = 0; i < 3; ++i) {
            gld_lds16(vp_[i], (short*)sV + (i * 256 + wave * 64) * 8);
            vp_[i] += 64;
        }

        __syncthreads();  // drains vmcnt: tiles ready

        // QK^T + exp, one 16-wide p-subtile at a time (kf transient)
#pragma unroll
        for (int j = 0; j < 4; ++j) {
            short8 kf[3];
#pragma unroll
            for (int kc = 0; kc < 3; ++kc)
                kf[kc] = *(const short8*)((const short*)sK + j * 2048 + kB[kc]);
            f32x4 s0 = (f32x4){0.f, 0.f, 0.f, 0.f};
            f32x4 s1 = (f32x4){0.f, 0.f, 0.f, 0.f};
            s0 = mfma16(aq[0][0], kf[0], s0);
            s1 = mfma16(aq[1][0], kf[0], s1);
            s0 = mfma16(aq[0][1], kf[1], s0);
            s1 = mfma16(aq[1][1], kf[1], s1);
            s0 = mfma16(aq[0][2], kf[2], s0);
            s1 = mfma16(aq[1][2], kf[2], s1);
#pragma unroll
            for (int r = 0; r < 4; ++r) {
                const float e0 = __expf(s0[r] * scale);
                const float e1 = __expf(s1[r] * scale);
                li[0][r] += e0;
                li[1][r] += e1;
                Pl[wave][quad * 4 + r][j * 16 + l16]      = f2bs(e0);
                Pl[wave][16 + quad * 4 + r][j * 16 + l16] = f2bs(e1);
            }
        }

        __builtin_amdgcn_s_waitcnt(0xc07f);  // lgkmcnt(0): P transpose done

        short8 ap[2][2];
#pragma unroll
        for (int mf = 0; mf < 2; ++mf)
#pragma unroll
            for (int kv = 0; kv < 2; ++kv)
                ap[mf][kv] = *(const short8*)
                    &Pl[wave][mf * 16 + l16][kv * 32 + quad * 8];

#pragma unroll
        for (int nt = 0; nt < 6; ++nt) {
#pragma unroll
            for (int kv = 0; kv < 2; ++kv) {
                const short8 v =
                    *(const short8*)((const short*)sV + nt * 1024 + vB[kv]);
                o[0][nt] = mfma16(ap[0][kv], v, o[0][nt]);
                o[1][nt] = mfma16(ap[1][kv], v, o[1][nt]);
            }
        }
    }

#pragma unroll
    for (int mf = 0; mf < 2; ++mf) {
        float inv[4];
#pragma unroll
        for (int r = 0; r < 4; ++r) {
#pragma unroll
            for (int off = 1; off < 16; off <<= 1)
                li[mf][r] += __shfl_xor(li[mf][r], off, 16);
            inv[r] = 1.0f / li[mf][r];
        }
#pragma unroll
        for (int nt = 0; nt < 6; ++nt)
#pragma unroll
            for (int r = 0; r < 4; ++r)
                att[(brow + m0 + mf * 16 + quad * 4 + r) * 768 + h * 96 +
                    nt * 16 + l16] = f2bs(o[mf][nt][r] * inv[r]);
        if (l16 == 0) {
#pragma unroll
            for (int r = 0; r < 4; ++r)
                linv[(((size_t)b * 8 + h) << 10) + m0 + mf * 16 + quad * 4 + r] =
                    inv[r];
        }
    }
}

// ---------------------------------------------------------------------------
// Head-averaged attention map, gemm-pattern 2-barrier DMA structure (proven).
// ---------------------------------------------------------------------------
__global__ __launch_bounds__(256) void attn_avg5(const short* __restrict__ Q,
                                                 const short* __restrict__ K,
                                                 const float* __restrict__ linv,
                                                 float* __restrict__ avg) {
    __shared__ short sQ[12][128][8];  // 24 KB
    __shared__ short sK[12][128][8];  // 24 KB

    const int pt = blockIdx.x;
    const int mt = blockIdx.y;
    const int b  = blockIdx.z;
    const int tid  = threadIdx.x;
    const int wave = tid >> 6;
    const int lane = tid & 63;
    const int quad = lane >> 4;
    const int l16  = lane & 15;

    const int m0 = mt * 128;
    const int p0 = pt * 128;
    const size_t brow = (size_t)b * 1024;
    const int wm = (wave & 1) * 64;
    const int wn = (wave >> 1) * 64;
    const float scale2 = 0.14724445f;  // (1/sqrt(96)) * log2(e)

    const short* Qsrc = Q + (brow + m0 + lane) * 768;
    const short* Ksrc = K + (brow + p0 + lane) * 768;
    const float* Lb_  = linv + (((size_t)b * 8) << 10) + m0 + wm + quad * 4;

    f32x4 acc[4][4];
#pragma unroll
    for (int x = 0; x < 4; ++x)
#pragma unroll
        for (int y = 0; y < 4; ++y) acc[x][y] = (f32x4){0.f, 0.f, 0.f, 0.f};

#pragma unroll 1
    for (int h = 0; h < 8; ++h) {
        __syncthreads();

#pragma unroll
        for (int i = 0; i < 6; ++i) {
            const int j = wave * 6 + i;
            const int c = j >> 1, half = j & 1;
            gld_lds16(Qsrc + (size_t)(half * 64) * 768 + h * 96 + c * 8,
                      &sQ[c][half * 64][0]);
            gld_lds16(Ksrc + (size_t)(half * 64) * 768 + h * 96 + c * 8,
                      &sK[c][half * 64][0]);
        }

        f32x4 il[4];
#pragma unroll
        for (int x = 0; x < 4; ++x)
            il[x] = 0.125f * *(const f32x4*)(Lb_ + ((size_t)h << 10) + x * 16);

        __syncthreads();

        short8 af[4][3], bf[4][3];
#pragma unroll
        for (int x = 0; x < 4; ++x)
#pragma unroll
            for (int kc = 0; kc < 3; ++kc) {
                af[x][kc] = *(const short8*)&sQ[kc * 4 + quad][wm + x * 16 + l16][0];
                bf[x][kc] = *(const short8*)&sK[kc * 4 + quad][wn + x * 16 + l16][0];
            }

#pragma unroll
        for (int x = 0; x < 4; ++x)
#pragma unroll
            for (int y = 0; y < 4; ++y) {
                f32x4 s = (f32x4){0.f, 0.f, 0.f, 0.f};
                s = mfma16(af[x][0], bf[y][0], s);
                s = mfma16(af[x][1], bf[y][1], s);
                s = mfma16(af[x][2], bf[y][2], s);
#pragma unroll
                for (int r = 0; r < 4; ++r)
                    acc[x][y][r] += __builtin_exp2f(s[r] * scale2) * il[x][r];
            }
    }

#pragma unroll
    for (int x = 0; x < 4; ++x)
#pragma unroll
        for (int y = 0; y < 4; ++y)
#pragma unroll
            for (int r = 0; r < 4; ++r)
                avg[(brow + m0 + wm + x * 16 + quad * 4 + r) * 1024 +
                    p0 + wn + y * 16 + l16] = acc[x][y][r];
}

extern "C" void kernel_launch(void* const* d_in, const int* in_sizes, int n_in,
                              void* d_out, int out_size, void* d_ws, size_t ws_size,
                              hipStream_t stream) {
    (void)in_sizes; (void)n_in; (void)out_size; (void)d_ws; (void)ws_size;

    float* mam = (float*)d_in[0];
    float* pat = (float*)d_in[1];
    const float* qw = (const float*)d_in[2];
    const float* qb = (const float*)d_in[3];
    const float* kw = (const float*)d_in[4];
    const float* kb = (const float*)d_in[5];
    const float* vw = (const float*)d_in[6];
    const float* vb = (const float*)d_in[7];
    const float* ow = (const float*)d_in[8];
    const float* ob = (const float*)d_in[9];

    const size_t NTOK = (size_t)8 * 1024 * 768;
    float* out_att = (float*)d_out;
    float* out_avg = out_att + NTOK;

    short* Am = (short*)d_out;           // bf16 mammo  @ out_att head (dead after Q-proj)
    short* Ap = (short*)out_avg;         // bf16 patho  @ out_avg head (dead after V-proj)
    short* Qb = (short*)mam;             // bf16 Q      @ mammo[0:NTOK]
    short* Kb = Qb + NTOK;               // bf16 K      @ mammo[NTOK:2*NTOK]
    short* Vt = (short*)pat;             // bf16 Vt     @ patho[0:NTOK]
    short* Ab = Vt + NTOK;               // bf16 att    @ patho[NTOK:2*NTOK]
    float* LV = (float*)(Am + NTOK);     // 1/l (256KB) @ out_att tail (dead before O-proj)

    dim3 bb(256), gg(6, 64);
    cvt_b16<<<3072, bb, 0, stream>>>(mam, Am);
    cvt_b16<<<3072, bb, 0, stream>>>(pat, Ap);
    gemm_mfma<<<gg, bb, 0, stream>>>(Am, qw, qb, Qb, 0);
    gemm_mfma<<<gg, bb, 0, stream>>>(Ap, kw, kb, Kb, 0);
    gemm_mfma<<<gg, bb, 0, stream>>>(Ap, vw, vb, Vt, 1);

    flash_att<<<dim3(8, 8, 8), bb, 0, stream>>>(Qb, Kb, Vt, Ab, LV);
    attn_avg5<<<dim3(8, 8, 8), bb, 0, stream>>>(Qb, Kb, LV, out_avg);

    gemm_mfma<<<gg, bb, 0, stream>>>(Ab, ow, ob, out_att, 2);
}

// Round 8
// 356.748 us; speedup vs baseline: 1.4459x; 1.0945x over previous
//
#include <hip/hip_runtime.h>

typedef short short8 __attribute__((ext_vector_type(8)));
typedef float f32x4 __attribute__((ext_vector_type(4)));

__device__ __forceinline__ f32x4 mfma16(short8 a, short8 b, f32x4 c) {
    return __builtin_amdgcn_mfma_f32_16x16x32_bf16(a, b, c, 0, 0, 0);
}
__device__ __forceinline__ short f2bs(float f) {
    __bf16 h = (__bf16)f;
    return __builtin_bit_cast(short, h);
}
__device__ __forceinline__ void gld_lds16(const void* g, void* l) {
    __builtin_amdgcn_global_load_lds(
        (const __attribute__((address_space(1))) void*)g,
        (__attribute__((address_space(3))) void*)l, 16, 0, 0);
}

// ---------------------------------------------------------------------------
// fp32 -> bf16 bulk convert (8 elems/thread)
// ---------------------------------------------------------------------------
__global__ __launch_bounds__(256) void cvt_b16(const float* __restrict__ in,
                                               short* __restrict__ out) {
    const size_t i = ((size_t)blockIdx.x * 256 + threadIdx.x) * 8;
    const float4 v0 = *(const float4*)(in + i);
    const float4 v1 = *(const float4*)(in + i + 4);
    short8 s;
    s[0] = f2bs(v0.x); s[1] = f2bs(v0.y); s[2] = f2bs(v0.z); s[3] = f2bs(v0.w);
    s[4] = f2bs(v1.x); s[5] = f2bs(v1.y); s[6] = f2bs(v1.z); s[7] = f2bs(v1.w);
    *(short8*)(out + i) = s;
}

// ---------------------------------------------------------------------------
// MFMA GEMM-BT: C[r][n] = sum_k A[r][k]*W[n][k] + bias[n]
// mode 0: C bf16 row-major; mode 1: C bf16 Vt[b][768][1024]; mode 2: C fp32;
// mode 3: C bf16 chunk-plane head-major QH[h][c][t][8] = ((h*12+c)*8192+t)*8+e
//         (h = n/96, c = (n%96)/8, e = n%8) -> a head's tile is DMA-contiguous.
// ---------------------------------------------------------------------------
__global__ __launch_bounds__(256) void gemm_mfma(const short* __restrict__ A,
                                                 const float* __restrict__ W,
                                                 const float* __restrict__ bias,
                                                 void* __restrict__ Cv,
                                                 int mode) {
    __shared__ short sA[128][64];
    __shared__ short sW[128][64];

    const int tid = threadIdx.x;
    const int wave = tid >> 6, lane = tid & 63;
    const int quad = lane >> 4, l16 = lane & 15;
    const int n0 = blockIdx.x * 128;
    const int r0 = blockIdx.y * 128;
    const int wm = (wave & 1) * 64;
    const int wn = (wave >> 1) * 64;

    const int lrow   = lane >> 3;
    const int lchunk = (lane & 7) ^ lrow;
    const short* Abase =
        A + (size_t)(r0 + wave * 32 + lrow) * 768 + lchunk * 8;

    const int wrow = tid >> 1;
    const int wseg = tid & 1;
    const float* Wbase = W + (size_t)(n0 + wrow) * 768 + wseg * 32;
    const int wsw = wrow & 7;

    f32x4 acc[4][4];
#pragma unroll
    for (int mt = 0; mt < 4; ++mt)
#pragma unroll
        for (int nt = 0; nt < 4; ++nt) acc[mt][nt] = (f32x4){0.f, 0.f, 0.f, 0.f};

    for (int k0 = 0; k0 < 768; k0 += 64) {
        float4 wv[8];
#pragma unroll
        for (int j = 0; j < 8; ++j)
            wv[j] = *(const float4*)(Wbase + k0 + j * 4);

        __syncthreads();

#pragma unroll
        for (int i = 0; i < 4; ++i)
            gld_lds16(Abase + k0 + (size_t)i * 8 * 768,
                      &sA[(wave * 4 + i) * 8][0]);

#pragma unroll
        for (int c = 0; c < 4; ++c) {
            const float4 a = wv[2 * c], b = wv[2 * c + 1];
            short8 p;
            p[0] = f2bs(a.x); p[1] = f2bs(a.y); p[2] = f2bs(a.z); p[3] = f2bs(a.w);
            p[4] = f2bs(b.x); p[5] = f2bs(b.y); p[6] = f2bs(b.z); p[7] = f2bs(b.w);
            *(short8*)&sW[wrow][((wseg * 4 + c) ^ wsw) * 8] = p;
        }

        __syncthreads();

#pragma unroll
        for (int ks = 0; ks < 2; ++ks) {
            short8 af[4], bf[4];
#pragma unroll
            for (int mt = 0; mt < 4; ++mt)
                af[mt] = *(const short8*)
                    &sA[wm + mt * 16 + l16][((ks * 4 + quad) ^ (l16 & 7)) * 8];
#pragma unroll
            for (int nt = 0; nt < 4; ++nt)
                bf[nt] = *(const short8*)
                    &sW[wn + nt * 16 + l16][((ks * 4 + quad) ^ (l16 & 7)) * 8];
#pragma unroll
            for (int mt = 0; mt < 4; ++mt)
#pragma unroll
                for (int nt = 0; nt < 4; ++nt)
                    acc[mt][nt] = mfma16(af[mt], bf[nt], acc[mt][nt]);
        }
    }

    short* Cs = (short*)Cv;
    float* Cf = (float*)Cv;
#pragma unroll
    for (int nt = 0; nt < 4; ++nt) {
        const int n = n0 + wn + nt * 16 + l16;
        const float bv = bias[n];
        const size_t hcb = (size_t)((n / 96) * 12 + ((n % 96) >> 3)) * 65536 +
                           (n % 8);
#pragma unroll
        for (int mt = 0; mt < 4; ++mt) {
#pragma unroll
            for (int rr = 0; rr < 4; ++rr) {
                const int row = r0 + wm + mt * 16 + quad * 4 + rr;
                const float val = acc[mt][nt][rr] + bv;
                if (mode == 0) {
                    Cs[(size_t)row * 768 + n] = f2bs(val);
                } else if (mode == 1) {
                    Cs[((size_t)(row >> 10) * 768 + n) * 1024 + (row & 1023)] = f2bs(val);
                } else if (mode == 3) {
                    Cs[hcb + (size_t)row * 8] = f2bs(val);
                } else {
                    Cf[(size_t)row * 768 + n] = val;
                }
            }
        }
    }
}

// ---------------------------------------------------------------------------
// Flash attention, round-7: K read from chunk-plane QH/KH layout ->
// K staging is 12 plane-contiguous 1KB DMAs into sKp[12][64][8] (the
// proven zero-conflict chunk-plane read pattern; no XOR, no clamp).
// Q register reads re-indexed for the plane layout. V / P-transpose /
// output identical to round-6. Grid (8h, 8mt, 8b), h on x = XCD locality.
// ---------------------------------------------------------------------------
__global__ __launch_bounds__(256) void flash_att(const short* __restrict__ QH,
                                                 const short* __restrict__ KH,
                                                 const short* __restrict__ Vt,
                                                 short* __restrict__ att,
                                                 float* __restrict__ linv) {
    __shared__ short sKp[12][64][8];  // 12 KB
    __shared__ short sV[96][8][8];    // 12 KB
    __shared__ short Pl[4][32][76];   // 19 KB

    const int h  = blockIdx.x;   // XCD selector
    const int mt = blockIdx.y;
    const int b  = blockIdx.z;
    const int tid  = threadIdx.x;
    const int wave = tid >> 6;
    const int lane = tid & 63;
    const int quad = lane >> 4;
    const int l16  = lane & 15;

    const int m0 = mt * 128 + wave * 32;
    const size_t brow = (size_t)b * 1024;
    const float scale = 0.1020620726159657f;  // 1/sqrt(96)

    // Q fragments from chunk-plane layout: chunk c = kc*4+quad
    short8 aq[2][3];
#pragma unroll
    for (int mf = 0; mf < 2; ++mf)
#pragma unroll
        for (int kc = 0; kc < 3; ++kc)
            aq[mf][kc] = *(const short8*)(QH +
                ((size_t)(h * 12 + kc * 4 + quad) * 8192 + brow + m0 +
                 mf * 16 + l16) * 8);

    // K plane DMA sources: instr i covers plane wave*3+i, lane -> row p0+lane
    const short* kp_[3];
#pragma unroll
    for (int i = 0; i < 3; ++i)
        kp_[i] = KH + ((size_t)(h * 12 + wave * 3 + i) * 8192 + brow + lane) * 8;

    // V: 768 slots, row=slot>>3 (d), chunkpos=slot&7, g = chunkpos^(row&7).
    const short* vp_[3];
#pragma unroll
    for (int i = 0; i < 3; ++i) {
        const int slot = i * 256 + tid;
        const int row = slot >> 3;
        const int g = (slot & 7) ^ (row & 7);
        vp_[i] = Vt + ((size_t)b * 768 + h * 96 + row) * 1024 + g * 8;
    }

    int vB[2];
#pragma unroll
    for (int kv = 0; kv < 2; ++kv)
        vB[kv] = l16 * 64 + (((kv * 4 + quad) ^ (l16 & 7)) * 8);

    f32x4 o[2][6];
#pragma unroll
    for (int mf = 0; mf < 2; ++mf)
#pragma unroll
        for (int nt = 0; nt < 6; ++nt) o[mf][nt] = (f32x4){0.f, 0.f, 0.f, 0.f};
    float li[2][4] = {};

    for (int p0 = 0; p0 < 1024; p0 += 64) {
        __syncthreads();  // all waves done reading previous tiles

#pragma unroll
        for (int i = 0; i < 3; ++i) {
            gld_lds16(kp_[i], &sKp[wave * 3 + i][0][0]);
            kp_[i] += 64 * 8;
        }
#pragma unroll
        for (int i = 0; i < 3; ++i) {
            gld_lds16(vp_[i], (short*)sV + (i * 256 + wave * 64) * 8);
            vp_[i] += 64;
        }

        __syncthreads();  // drains vmcnt: tiles ready

        // QK^T + exp, one 16-wide p-subtile at a time
#pragma unroll
        for (int j = 0; j < 4; ++j) {
            short8 kf[3];
#pragma unroll
            for (int kc = 0; kc < 3; ++kc)
                kf[kc] = *(const short8*)((const short*)sKp +
                    ((kc * 4 + quad) * 64 + j * 16 + l16) * 8);
            f32x4 s0 = (f32x4){0.f, 0.f, 0.f, 0.f};
            f32x4 s1 = (f32x4){0.f, 0.f, 0.f, 0.f};
            s0 = mfma16(aq[0][0], kf[0], s0);
            s1 = mfma16(aq[1][0], kf[0], s1);
            s0 = mfma16(aq[0][1], kf[1], s0);
            s1 = mfma16(aq[1][1], kf[1], s1);
            s0 = mfma16(aq[0][2], kf[2], s0);
            s1 = mfma16(aq[1][2], kf[2], s1);
#pragma unroll
            for (int r = 0; r < 4; ++r) {
                const float e0 = __expf(s0[r] * scale);
                const float e1 = __expf(s1[r] * scale);
                li[0][r] += e0;
                li[1][r] += e1;
                Pl[wave][quad * 4 + r][j * 16 + l16]      = f2bs(e0);
                Pl[wave][16 + quad * 4 + r][j * 16 + l16] = f2bs(e1);
            }
        }

        __builtin_amdgcn_s_waitcnt(0xc07f);  // lgkmcnt(0): P transpose done

        short8 ap[2][2];
#pragma unroll
        for (int mf = 0; mf < 2; ++mf)
#pragma unroll
            for (int kv = 0; kv < 2; ++kv)
                ap[mf][kv] = *(const short8*)
                    &Pl[wave][mf * 16 + l16][kv * 32 + quad * 8];

#pragma unroll
        for (int nt = 0; nt < 6; ++nt) {
#pragma unroll
            for (int kv = 0; kv < 2; ++kv) {
                const short8 v =
                    *(const short8*)((const short*)sV + nt * 1024 + vB[kv]);
                o[0][nt] = mfma16(ap[0][kv], v, o[0][nt]);
                o[1][nt] = mfma16(ap[1][kv], v, o[1][nt]);
            }
        }
    }

#pragma unroll
    for (int mf = 0; mf < 2; ++mf) {
        float inv[4];
#pragma unroll
        for (int r = 0; r < 4; ++r) {
#pragma unroll
            for (int off = 1; off < 16; off <<= 1)
                li[mf][r] += __shfl_xor(li[mf][r], off, 16);
            inv[r] = 1.0f / li[mf][r];
        }
#pragma unroll
        for (int nt = 0; nt < 6; ++nt)
#pragma unroll
            for (int r = 0; r < 4; ++r)
                att[(brow + m0 + mf * 16 + quad * 4 + r) * 768 + h * 96 +
                    nt * 16 + l16] = f2bs(o[mf][nt][r] * inv[r]);
        if (l16 == 0) {
#pragma unroll
            for (int r = 0; r < 4; ++r)
                linv[(((size_t)b * 8 + h) << 10) + m0 + mf * 16 + quad * 4 + r] =
                    inv[r];
        }
    }
}

// ---------------------------------------------------------------------------
// Head-averaged attention map, round-7: identical structure/LDS/reads to
// the proven attn_avg5; ONLY the DMA sources change — chunk-plane QH/KH
// makes every instruction a fully-contiguous 1KB read (was a 64-line
// row-gather). Grid (8 pt, 8 mt, 8 b) = 512 blocks.
// ---------------------------------------------------------------------------
__global__ __launch_bounds__(256) void attn_avg6(const short* __restrict__ QH,
                                                 const short* __restrict__ KH,
                                                 const float* __restrict__ linv,
                                                 float* __restrict__ avg) {
    __shared__ short sQ[12][128][8];  // 24 KB
    __shared__ short sK[12][128][8];  // 24 KB

    const int pt = blockIdx.x;
    const int mt = blockIdx.y;
    const int b  = blockIdx.z;
    const int tid  = threadIdx.x;
    const int wave = tid >> 6;
    const int lane = tid & 63;
    const int quad = lane >> 4;
    const int l16  = lane & 15;

    const int m0 = mt * 128;
    const int p0 = pt * 128;
    const size_t brow = (size_t)b * 1024;
    const int wm = (wave & 1) * 64;
    const int wn = (wave >> 1) * 64;
    const float scale2 = 0.14724445f;  // (1/sqrt(96)) * log2(e)

    const size_t qoff = (size_t)(brow + m0 + lane) * 8;
    const size_t koff = (size_t)(brow + p0 + lane) * 8;
    const float* Lb_  = linv + (((size_t)b * 8) << 10) + m0 + wm + quad * 4;

    f32x4 acc[4][4];
#pragma unroll
    for (int x = 0; x < 4; ++x)
#pragma unroll
        for (int y = 0; y < 4; ++y) acc[x][y] = (f32x4){0.f, 0.f, 0.f, 0.f};

#pragma unroll 1
    for (int h = 0; h < 8; ++h) {
        __syncthreads();

#pragma unroll
        for (int i = 0; i < 6; ++i) {
            const int j = wave * 6 + i;
            const int c = j >> 1, half = j & 1;
            const size_t pl = (size_t)(h * 12 + c) * 65536 + half * 512;
            gld_lds16(QH + pl + qoff, &sQ[c][half * 64][0]);
            gld_lds16(KH + pl + koff, &sK[c][half * 64][0]);
        }

        f32x4 il[4];
#pragma unroll
        for (int x = 0; x < 4; ++x)
            il[x] = 0.125f * *(const f32x4*)(Lb_ + ((size_t)h << 10) + x * 16);

        __syncthreads();

        short8 af[4][3], bf[4][3];
#pragma unroll
        for (int x = 0; x < 4; ++x)
#pragma unroll
            for (int kc = 0; kc < 3; ++kc) {
                af[x][kc] = *(const short8*)&sQ[kc * 4 + quad][wm + x * 16 + l16][0];
                bf[x][kc] = *(const short8*)&sK[kc * 4 + quad][wn + x * 16 + l16][0];
            }

#pragma unroll
        for (int x = 0; x < 4; ++x)
#pragma unroll
            for (int y = 0; y < 4; ++y) {
                f32x4 s = (f32x4){0.f, 0.f, 0.f, 0.f};
                s = mfma16(af[x][0], bf[y][0], s);
                s = mfma16(af[x][1], bf[y][1], s);
                s = mfma16(af[x][2], bf[y][2], s);
#pragma unroll
                for (int r = 0; r < 4; ++r)
                    acc[x][y][r] += __builtin_exp2f(s[r] * scale2) * il[x][r];
            }
    }

#pragma unroll
    for (int x = 0; x < 4; ++x)
#pragma unroll
        for (int y = 0; y < 4; ++y)
#pragma unroll
            for (int r = 0; r < 4; ++r)
                avg[(brow + m0 + wm + x * 16 + quad * 4 + r) * 1024 +
                    p0 + wn + y * 16 + l16] = acc[x][y][r];
}

extern "C" void kernel_launch(void* const* d_in, const int* in_sizes, int n_in,
                              void* d_out, int out_size, void* d_ws, size_t ws_size,
                              hipStream_t stream) {
    (void)in_sizes; (void)n_in; (void)out_size; (void)d_ws; (void)ws_size;

    float* mam = (float*)d_in[0];
    float* pat = (float*)d_in[1];
    const float* qw = (const float*)d_in[2];
    const float* qb = (const float*)d_in[3];
    const float* kw = (const float*)d_in[4];
    const float* kb = (const float*)d_in[5];
    const float* vw = (const float*)d_in[6];
    const float* vb = (const float*)d_in[7];
    const float* ow = (const float*)d_in[8];
    const float* ob = (const float*)d_in[9];

    const size_t NTOK = (size_t)8 * 1024 * 768;
    float* out_att = (float*)d_out;
    float* out_avg = out_att + NTOK;

    short* Am = (short*)d_out;           // bf16 mammo  @ out_att head (dead after Q-proj)
    short* Ap = (short*)out_avg;         // bf16 patho  @ out_avg head (dead after V-proj)
    short* Qh = (short*)mam;             // bf16 Q chunk-plane @ mammo[0:NTOK]
    short* Kh = Qh + NTOK;               // bf16 K chunk-plane @ mammo[NTOK:2*NTOK]
    short* Vt = (short*)pat;             // bf16 Vt     @ patho[0:NTOK]
    short* Ab = Vt + NTOK;               // bf16 att    @ patho[NTOK:2*NTOK]
    float* LV = (float*)(Am + NTOK);     // 1/l (256KB) @ out_att tail (dead before O-proj)

    dim3 bb(256), gg(6, 64);
    cvt_b16<<<3072, bb, 0, stream>>>(mam, Am);
    cvt_b16<<<3072, bb, 0, stream>>>(pat, Ap);
    gemm_mfma<<<gg, bb, 0, stream>>>(Am, qw, qb, Qh, 3);
    gemm_mfma<<<gg, bb, 0, stream>>>(Ap, kw, kb, Kh, 3);
    gemm_mfma<<<gg, bb, 0, stream>>>(Ap, vw, vb, Vt, 1);

    flash_att<<<dim3(8, 8, 8), bb, 0, stream>>>(Qh, Kh, Vt, Ab, LV);
    attn_avg6<<<dim3(8, 8, 8), bb, 0, stream>>>(Qh, Kh, LV, out_avg);

    gemm_mfma<<<gg, bb, 0, stream>>>(Ab, ow, ob, out_att, 2);
}

// Round 9
// 334.097 us; speedup vs baseline: 1.5439x; 1.0678x over previous
//
#include <hip/hip_runtime.h>

typedef short short4v __attribute__((ext_vector_type(4)));
typedef short short8 __attribute__((ext_vector_type(8)));
typedef float f32x4 __attribute__((ext_vector_type(4)));

__device__ __forceinline__ f32x4 mfma16(short8 a, short8 b, f32x4 c) {
    return __builtin_amdgcn_mfma_f32_16x16x32_bf16(a, b, c, 0, 0, 0);
}
__device__ __forceinline__ short f2bs(float f) {
    __bf16 h = (__bf16)f;
    return __builtin_bit_cast(short, h);
}
__device__ __forceinline__ void gld_lds16(const void* g, void* l) {
    __builtin_amdgcn_global_load_lds(
        (const __attribute__((address_space(1))) void*)g,
        (__attribute__((address_space(3))) void*)l, 16, 0, 0);
}

// ---------------------------------------------------------------------------
// fp32 -> bf16 bulk convert (8 elems/thread)
// ---------------------------------------------------------------------------
__global__ __launch_bounds__(256) void cvt_b16(const float* __restrict__ in,
                                               short* __restrict__ out) {
    const size_t i = ((size_t)blockIdx.x * 256 + threadIdx.x) * 8;
    const float4 v0 = *(const float4*)(in + i);
    const float4 v1 = *(const float4*)(in + i + 4);
    short8 s;
    s[0] = f2bs(v0.x); s[1] = f2bs(v0.y); s[2] = f2bs(v0.z); s[3] = f2bs(v0.w);
    s[4] = f2bs(v1.x); s[5] = f2bs(v1.y); s[6] = f2bs(v1.z); s[7] = f2bs(v1.w);
    *(short8*)(out + i) = s;
}

// ---------------------------------------------------------------------------
// MFMA GEMM-BT: C[r][n] = sum_k A[r][k]*W[n][k] + bias[n]
// mode 0: C bf16 row-major; mode 2: C fp32;
// mode 1: C bf16 Vt[b][768][1024] via LDS-transposed COALESCED epilogue
//         (round-8: was per-lane 2B stores at 2KB stride = ~16x write
//          amplification; now 256B-contiguous rows);
// mode 3: C bf16 chunk-plane head-major QH[h][c][t][8].
// ---------------------------------------------------------------------------
__global__ __launch_bounds__(256) void gemm_mfma(const short* __restrict__ A,
                                                 const float* __restrict__ W,
                                                 const float* __restrict__ bias,
                                                 void* __restrict__ Cv,
                                                 int mode) {
    __shared__ short sBuf[2][128][64];   // sA = sBuf[0], sW = sBuf[1]

    const int tid = threadIdx.x;
    const int wave = tid >> 6, lane = tid & 63;
    const int quad = lane >> 4, l16 = lane & 15;
    const int n0 = blockIdx.x * 128;
    const int r0 = blockIdx.y * 128;
    const int wm = (wave & 1) * 64;
    const int wn = (wave >> 1) * 64;

    const int lrow   = lane >> 3;
    const int lchunk = (lane & 7) ^ lrow;
    const short* Abase =
        A + (size_t)(r0 + wave * 32 + lrow) * 768 + lchunk * 8;

    const int wrow = tid >> 1;
    const int wseg = tid & 1;
    const float* Wbase = W + (size_t)(n0 + wrow) * 768 + wseg * 32;
    const int wsw = wrow & 7;

    f32x4 acc[4][4];
#pragma unroll
    for (int mt = 0; mt < 4; ++mt)
#pragma unroll
        for (int nt = 0; nt < 4; ++nt) acc[mt][nt] = (f32x4){0.f, 0.f, 0.f, 0.f};

    for (int k0 = 0; k0 < 768; k0 += 64) {
        float4 wv[8];
#pragma unroll
        for (int j = 0; j < 8; ++j)
            wv[j] = *(const float4*)(Wbase + k0 + j * 4);

        __syncthreads();

#pragma unroll
        for (int i = 0; i < 4; ++i)
            gld_lds16(Abase + k0 + (size_t)i * 8 * 768,
                      &sBuf[0][(wave * 4 + i) * 8][0]);

#pragma unroll
        for (int c = 0; c < 4; ++c) {
            const float4 a = wv[2 * c], b = wv[2 * c + 1];
            short8 p;
            p[0] = f2bs(a.x); p[1] = f2bs(a.y); p[2] = f2bs(a.z); p[3] = f2bs(a.w);
            p[4] = f2bs(b.x); p[5] = f2bs(b.y); p[6] = f2bs(b.z); p[7] = f2bs(b.w);
            *(short8*)&sBuf[1][wrow][((wseg * 4 + c) ^ wsw) * 8] = p;
        }

        __syncthreads();

#pragma unroll
        for (int ks = 0; ks < 2; ++ks) {
            short8 af[4], bf[4];
#pragma unroll
            for (int mt = 0; mt < 4; ++mt)
                af[mt] = *(const short8*)
                    &sBuf[0][wm + mt * 16 + l16][((ks * 4 + quad) ^ (l16 & 7)) * 8];
#pragma unroll
            for (int nt = 0; nt < 4; ++nt)
                bf[nt] = *(const short8*)
                    &sBuf[1][wn + nt * 16 + l16][((ks * 4 + quad) ^ (l16 & 7)) * 8];
#pragma unroll
            for (int mt = 0; mt < 4; ++mt)
#pragma unroll
                for (int nt = 0; nt < 4; ++nt)
                    acc[mt][nt] = mfma16(af[mt], bf[nt], acc[mt][nt]);
        }
    }

    short* Cs = (short*)Cv;
    float* Cf = (float*)Cv;

    if (mode == 1) {
        // Coalesced Vt epilogue. Output region Vt[b_][n0..n0+128][p0v..p0v+128].
        // Two passes over n-halves; tile [64 n][132 p] shorts in sBuf.
        short* tl = &sBuf[0][0][0];          // 8448 of 16384 shorts used
        const int b_  = r0 >> 10;
        const int p0v = r0 & 1023;
#pragma unroll 1
        for (int pass = 0; pass < 2; ++pass) {
            __syncthreads();   // previous reads of sBuf / tile done
            if ((wave >> 1) == pass) {
#pragma unroll
                for (int nt = 0; nt < 4; ++nt) {
                    const float bv = bias[n0 + wn + nt * 16 + l16];
#pragma unroll
                    for (int mt = 0; mt < 4; ++mt) {
                        short4v pk;
#pragma unroll
                        for (int rr = 0; rr < 4; ++rr)
                            pk[rr] = f2bs(acc[mt][nt][rr] + bv);
                        *(short4v*)&tl[(nt * 16 + l16) * 132 + wm + mt * 16 +
                                       quad * 4] = pk;
                    }
                }
            }
            __syncthreads();
            // store: row = tid>>2 (64 rows), seg = tid&3 (32 shorts each)
            const int row = tid >> 2, seg = tid & 3;
            const int n_g = n0 + pass * 64 + row;
            short* dst = Cs + ((size_t)(b_ * 768 + n_g) << 10) + p0v + seg * 32;
            const short* srcl = &tl[row * 132 + seg * 32];
#pragma unroll
            for (int u = 0; u < 4; ++u)
                *(short8*)(dst + u * 8) = *(const short8*)(srcl + u * 8);
        }
        return;
    }

#pragma unroll
    for (int nt = 0; nt < 4; ++nt) {
        const int n = n0 + wn + nt * 16 + l16;
        const float bv = bias[n];
        const size_t hcb = (size_t)((n / 96) * 12 + ((n % 96) >> 3)) * 65536 +
                           (n % 8);
#pragma unroll
        for (int mt = 0; mt < 4; ++mt) {
#pragma unroll
            for (int rr = 0; rr < 4; ++rr) {
                const int row = r0 + wm + mt * 16 + quad * 4 + rr;
                const float val = acc[mt][nt][rr] + bv;
                if (mode == 0) {
                    Cs[(size_t)row * 768 + n] = f2bs(val);
                } else if (mode == 3) {
                    Cs[hcb + (size_t)row * 8] = f2bs(val);
                } else {
                    Cf[(size_t)row * 768 + n] = val;
                }
            }
        }
    }
}

// ---------------------------------------------------------------------------
// Flash attention, round-8: 2-phase software pipeline (T3 minimum recipe) —
// stage tile t+1 into the ping-pong LDS buffer BEFORE computing tile t;
// ONE barrier per step (drains the in-flight DMA and closes the read window).
// DMA latency hides under 48 MFMA + 32 exp per wave. K/V sources and all
// compute identical to round-7 (chunk-plane K, swizzled V, P-LDS-transpose).
// LDS 67 KB -> 2 blocks/CU (grid 512 = 2/CU anyway).
// ---------------------------------------------------------------------------
__global__ __launch_bounds__(256) void flash_att(const short* __restrict__ QH,
                                                 const short* __restrict__ KH,
                                                 const short* __restrict__ Vt,
                                                 short* __restrict__ att,
                                                 float* __restrict__ linv) {
    __shared__ short sKp[2][12][64][8];  // 24 KB
    __shared__ short sV[2][96][8][8];    // 24 KB
    __shared__ short Pl[4][32][76];      // 19 KB

    const int h  = blockIdx.x;   // XCD selector
    const int mt = blockIdx.y;
    const int b  = blockIdx.z;
    const int tid  = threadIdx.x;
    const int wave = tid >> 6;
    const int lane = tid & 63;
    const int quad = lane >> 4;
    const int l16  = lane & 15;

    const int m0 = mt * 128 + wave * 32;
    const size_t brow = (size_t)b * 1024;
    const float scale = 0.1020620726159657f;  // 1/sqrt(96)

    short8 aq[2][3];
#pragma unroll
    for (int mf = 0; mf < 2; ++mf)
#pragma unroll
        for (int kc = 0; kc < 3; ++kc)
            aq[mf][kc] = *(const short8*)(QH +
                ((size_t)(h * 12 + kc * 4 + quad) * 8192 + brow + m0 +
                 mf * 16 + l16) * 8);

    const short* kp_[3];
#pragma unroll
    for (int i = 0; i < 3; ++i)
        kp_[i] = KH + ((size_t)(h * 12 + wave * 3 + i) * 8192 + brow + lane) * 8;

    const short* vp_[3];
#pragma unroll
    for (int i = 0; i < 3; ++i) {
        const int slot = i * 256 + tid;
        const int row = slot >> 3;
        const int g = (slot & 7) ^ (row & 7);
        vp_[i] = Vt + ((size_t)b * 768 + h * 96 + row) * 1024 + g * 8;
    }

    int vB[2];
#pragma unroll
    for (int kv = 0; kv < 2; ++kv)
        vB[kv] = l16 * 64 + (((kv * 4 + quad) ^ (l16 & 7)) * 8);

    f32x4 o[2][6];
#pragma unroll
    for (int mf = 0; mf < 2; ++mf)
#pragma unroll
        for (int nt = 0; nt < 6; ++nt) o[mf][nt] = (f32x4){0.f, 0.f, 0.f, 0.f};
    float li[2][4] = {};

#define FA_STAGE(BUF)                                                          \
    {                                                                          \
        _Pragma("unroll")                                                      \
        for (int i = 0; i < 3; ++i) {                                          \
            gld_lds16(kp_[i], &sKp[BUF][wave * 3 + i][0][0]);                  \
            kp_[i] += 512;                                                     \
        }                                                                      \
        _Pragma("unroll")                                                      \
        for (int i = 0; i < 3; ++i) {                                          \
            gld_lds16(vp_[i], (short*)sV[BUF] + (i * 256 + wave * 64) * 8);    \
            vp_[i] += 64;                                                      \
        }                                                                      \
    }

    // prologue: stage tile 0
    FA_STAGE(0)
    __syncthreads();

    int cur = 0;
#pragma unroll 1
    for (int t = 0; t < 16; ++t) {
        if (t < 15) FA_STAGE(cur ^ 1)   // next tile in flight during compute

        // ---- compute tile `cur` ----
#pragma unroll
        for (int j = 0; j < 4; ++j) {
            short8 kf[3];
#pragma unroll
            for (int kc = 0; kc < 3; ++kc)
                kf[kc] = *(const short8*)((const short*)sKp[cur] +
                    ((kc * 4 + quad) * 64 + j * 16 + l16) * 8);
            f32x4 s0 = (f32x4){0.f, 0.f, 0.f, 0.f};
            f32x4 s1 = (f32x4){0.f, 0.f, 0.f, 0.f};
            s0 = mfma16(aq[0][0], kf[0], s0);
            s1 = mfma16(aq[1][0], kf[0], s1);
            s0 = mfma16(aq[0][1], kf[1], s0);
            s1 = mfma16(aq[1][1], kf[1], s1);
            s0 = mfma16(aq[0][2], kf[2], s0);
            s1 = mfma16(aq[1][2], kf[2], s1);
#pragma unroll
            for (int r = 0; r < 4; ++r) {
                const float e0 = __expf(s0[r] * scale);
                const float e1 = __expf(s1[r] * scale);
                li[0][r] += e0;
                li[1][r] += e1;
                Pl[wave][quad * 4 + r][j * 16 + l16]      = f2bs(e0);
                Pl[wave][16 + quad * 4 + r][j * 16 + l16] = f2bs(e1);
            }
        }

        __builtin_amdgcn_s_waitcnt(0xc07f);  // lgkmcnt(0) only (vmcnt open)

        short8 ap[2][2];
#pragma unroll
        for (int mf = 0; mf < 2; ++mf)
#pragma unroll
            for (int kv = 0; kv < 2; ++kv)
                ap[mf][kv] = *(const short8*)
                    &Pl[wave][mf * 16 + l16][kv * 32 + quad * 8];

#pragma unroll
        for (int nt = 0; nt < 6; ++nt) {
#pragma unroll
            for (int kv = 0; kv < 2; ++kv) {
                const short8 v =
                    *(const short8*)((const short*)sV[cur] + nt * 1024 + vB[kv]);
                o[0][nt] = mfma16(ap[0][kv], v, o[0][nt]);
                o[1][nt] = mfma16(ap[1][kv], v, o[1][nt]);
            }
        }

        __syncthreads();  // next-tile DMA complete + this buffer's reads done
        cur ^= 1;
    }
#undef FA_STAGE

#pragma unroll
    for (int mf = 0; mf < 2; ++mf) {
        float inv[4];
#pragma unroll
        for (int r = 0; r < 4; ++r) {
#pragma unroll
            for (int off = 1; off < 16; off <<= 1)
                li[mf][r] += __shfl_xor(li[mf][r], off, 16);
            inv[r] = 1.0f / li[mf][r];
        }
#pragma unroll
        for (int nt = 0; nt < 6; ++nt)
#pragma unroll
            for (int r = 0; r < 4; ++r)
                att[(brow + m0 + mf * 16 + quad * 4 + r) * 768 + h * 96 +
                    nt * 16 + l16] = f2bs(o[mf][nt][r] * inv[r]);
        if (l16 == 0) {
#pragma unroll
            for (int r = 0; r < 4; ++r)
                linv[(((size_t)b * 8 + h) << 10) + m0 + mf * 16 + quad * 4 + r] =
                    inv[r];
        }
    }
}

// ---------------------------------------------------------------------------
// Head-averaged attention map (round-7 proven: chunk-plane contiguous DMA).
// ---------------------------------------------------------------------------
__global__ __launch_bounds__(256) void attn_avg6(const short* __restrict__ QH,
                                                 const short* __restrict__ KH,
                                                 const float* __restrict__ linv,
                                                 float* __restrict__ avg) {
    __shared__ short sQ[12][128][8];  // 24 KB
    __shared__ short sK[12][128][8];  // 24 KB

    const int pt = blockIdx.x;
    const int mt = blockIdx.y;
    const int b  = blockIdx.z;
    const int tid  = threadIdx.x;
    const int wave = tid >> 6;
    const int lane = tid & 63;
    const int quad = lane >> 4;
    const int l16  = lane & 15;

    const int m0 = mt * 128;
    const int p0 = pt * 128;
    const size_t brow = (size_t)b * 1024;
    const int wm = (wave & 1) * 64;
    const int wn = (wave >> 1) * 64;
    const float scale2 = 0.14724445f;  // (1/sqrt(96)) * log2(e)

    const size_t qoff = (size_t)(brow + m0 + lane) * 8;
    const size_t koff = (size_t)(brow + p0 + lane) * 8;
    const float* Lb_  = linv + (((size_t)b * 8) << 10) + m0 + wm + quad * 4;

    f32x4 acc[4][4];
#pragma unroll
    for (int x = 0; x < 4; ++x)
#pragma unroll
        for (int y = 0; y < 4; ++y) acc[x][y] = (f32x4){0.f, 0.f, 0.f, 0.f};

#pragma unroll 1
    for (int h = 0; h < 8; ++h) {
        __syncthreads();

#pragma unroll
        for (int i = 0; i < 6; ++i) {
            const int j = wave * 6 + i;
            const int c = j >> 1, half = j & 1;
            const size_t pl = (size_t)(h * 12 + c) * 65536 + half * 512;
            gld_lds16(QH + pl + qoff, &sQ[c][half * 64][0]);
            gld_lds16(KH + pl + koff, &sK[c][half * 64][0]);
        }

        f32x4 il[4];
#pragma unroll
        for (int x = 0; x < 4; ++x)
            il[x] = 0.125f * *(const f32x4*)(Lb_ + ((size_t)h << 10) + x * 16);

        __syncthreads();

        short8 af[4][3], bf[4][3];
#pragma unroll
        for (int x = 0; x < 4; ++x)
#pragma unroll
            for (int kc = 0; kc < 3; ++kc) {
                af[x][kc] = *(const short8*)&sQ[kc * 4 + quad][wm + x * 16 + l16][0];
                bf[x][kc] = *(const short8*)&sK[kc * 4 + quad][wn + x * 16 + l16][0];
            }

#pragma unroll
        for (int x = 0; x < 4; ++x)
#pragma unroll
            for (int y = 0; y < 4; ++y) {
                f32x4 s = (f32x4){0.f, 0.f, 0.f, 0.f};
                s = mfma16(af[x][0], bf[y][0], s);
                s = mfma16(af[x][1], bf[y][1], s);
                s = mfma16(af[x][2], bf[y][2], s);
#pragma unroll
                for (int r = 0; r < 4; ++r)
                    acc[x][y][r] += __builtin_exp2f(s[r] * scale2) * il[x][r];
            }
    }

#pragma unroll
    for (int x = 0; x < 4; ++x)
#pragma unroll
        for (int y = 0; y < 4; ++y)
#pragma unroll
            for (int r = 0; r < 4; ++r)
                avg[(brow + m0 + wm + x * 16 + quad * 4 + r) * 1024 +
                    p0 + wn + y * 16 + l16] = acc[x][y][r];
}

extern "C" void kernel_launch(void* const* d_in, const int* in_sizes, int n_in,
                              void* d_out, int out_size, void* d_ws, size_t ws_size,
                              hipStream_t stream) {
    (void)in_sizes; (void)n_in; (void)out_size; (void)d_ws; (void)ws_size;

    float* mam = (float*)d_in[0];
    float* pat = (float*)d_in[1];
    const float* qw = (const float*)d_in[2];
    const float* qb = (const float*)d_in[3];
    const float* kw = (const float*)d_in[4];
    const float* kb = (const float*)d_in[5];
    const float* vw = (const float*)d_in[6];
    const float* vb = (const float*)d_in[7];
    const float* ow = (const float*)d_in[8];
    const float* ob = (const float*)d_in[9];

    const size_t NTOK = (size_t)8 * 1024 * 768;
    float* out_att = (float*)d_out;
    float* out_avg = out_att + NTOK;

    short* Am = (short*)d_out;           // bf16 mammo  @ out_att head (dead after Q-proj)
    short* Ap = (short*)out_avg;         // bf16 patho  @ out_avg head (dead after V-proj)
    short* Qh = (short*)mam;             // bf16 Q chunk-plane @ mammo[0:NTOK]
    short* Kh = Qh + NTOK;               // bf16 K chunk-plane @ mammo[NTOK:2*NTOK]
    short* Vt = (short*)pat;             // bf16 Vt     @ patho[0:NTOK]
    short* Ab = Vt + NTOK;               // bf16 att    @ patho[NTOK:2*NTOK]
    float* LV = (float*)(Am + NTOK);     // 1/l (256KB) @ out_att tail (dead before O-proj)

    dim3 bb(256), gg(6, 64);
    cvt_b16<<<3072, bb, 0, stream>>>(mam, Am);
    cvt_b16<<<3072, bb, 0, stream>>>(pat, Ap);
    gemm_mfma<<<gg, bb, 0, stream>>>(Am, qw, qb, Qh, 3);
    gemm_mfma<<<gg, bb, 0, stream>>>(Ap, kw, kb, Kh, 3);
    gemm_mfma<<<gg, bb, 0, stream>>>(Ap, vw, vb, Vt, 1);

    flash_att<<<dim3(8, 8, 8), bb, 0, stream>>>(Qh, Kh, Vt, Ab, LV);
    attn_avg6<<<dim3(8, 8, 8), bb, 0, stream>>>(Qh, Kh, LV, out_avg);

    gemm_mfma<<<gg, bb, 0, stream>>>(Ab, ow, ob, out_att, 2);
}

// Round 10
// 294.759 us; speedup vs baseline: 1.7500x; 1.1335x over previous
//
#include <hip/hip_runtime.h>

typedef short short4v __attribute__((ext_vector_type(4)));
typedef short short8 __attribute__((ext_vector_type(8)));
typedef float f32x4 __attribute__((ext_vector_type(4)));

__device__ __forceinline__ f32x4 mfma16(short8 a, short8 b, f32x4 c) {
    return __builtin_amdgcn_mfma_f32_16x16x32_bf16(a, b, c, 0, 0, 0);
}
__device__ __forceinline__ short f2bs(float f) {
    __bf16 h = (__bf16)f;
    return __builtin_bit_cast(short, h);
}
__device__ __forceinline__ void gld_lds16(const void* g, void* l) {
    __builtin_amdgcn_global_load_lds(
        (const __attribute__((address_space(1))) void*)g,
        (__attribute__((address_space(3))) void*)l, 16, 0, 0);
}

// ---------------------------------------------------------------------------
// fp32 -> bf16 bulk convert (8 elems/thread)
// ---------------------------------------------------------------------------
__global__ __launch_bounds__(256) void cvt_b16(const float* __restrict__ in,
                                               short* __restrict__ out) {
    const size_t i = ((size_t)blockIdx.x * 256 + threadIdx.x) * 8;
    const float4 v0 = *(const float4*)(in + i);
    const float4 v1 = *(const float4*)(in + i + 4);
    short8 s;
    s[0] = f2bs(v0.x); s[1] = f2bs(v0.y); s[2] = f2bs(v0.z); s[3] = f2bs(v0.w);
    s[4] = f2bs(v1.x); s[5] = f2bs(v1.y); s[6] = f2bs(v1.z); s[7] = f2bs(v1.w);
    *(short8*)(out + i) = s;
}

// ---------------------------------------------------------------------------
// Round-9 gemm_bw: BOTH A and W bf16, BOTH staged via global_load_lds with
// the identical pre-swizzled-source chunk layout (pure m97 2-barrier shape:
// per K-step 8 DMA + 16 ds_read_b128 + 32 MFMA, zero staging VALU).
// mode 1: C bf16 Vt[b][768][1024] via LDS-transposed coalesced epilogue;
// mode 3: C bf16 chunk-plane head-major QH[h][c][t][8].
// ---------------------------------------------------------------------------
__global__ __launch_bounds__(256) void gemm_bw(const short* __restrict__ A,
                                               const short* __restrict__ Wb,
                                               const float* __restrict__ bias,
                                               void* __restrict__ Cv,
                                               int mode) {
    __shared__ short sBuf[2][128][64];

    const int tid = threadIdx.x;
    const int wave = tid >> 6, lane = tid & 63;
    const int quad = lane >> 4, l16 = lane & 15;
    const int n0 = blockIdx.x * 128;
    const int r0 = blockIdx.y * 128;
    const int wm = (wave & 1) * 64;
    const int wn = (wave >> 1) * 64;

    const int lrow   = lane >> 3;
    const int lchunk = (lane & 7) ^ lrow;
    const short* Abase =
        A + (size_t)(r0 + wave * 32 + lrow) * 768 + lchunk * 8;
    const short* Wbase =
        Wb + (size_t)(n0 + wave * 32 + lrow) * 768 + lchunk * 8;

    f32x4 acc[4][4];
#pragma unroll
    for (int mt = 0; mt < 4; ++mt)
#pragma unroll
        for (int nt = 0; nt < 4; ++nt) acc[mt][nt] = (f32x4){0.f, 0.f, 0.f, 0.f};

    for (int k0 = 0; k0 < 768; k0 += 64) {
        __syncthreads();  // all waves done reading previous tile

#pragma unroll
        for (int i = 0; i < 4; ++i) {
            gld_lds16(Abase + k0 + (size_t)i * 8 * 768,
                      &sBuf[0][(wave * 4 + i) * 8][0]);
            gld_lds16(Wbase + k0 + (size_t)i * 8 * 768,
                      &sBuf[1][(wave * 4 + i) * 8][0]);
        }

        __syncthreads();  // vmcnt drain: tiles ready

#pragma unroll
        for (int ks = 0; ks < 2; ++ks) {
            short8 af[4], bf[4];
#pragma unroll
            for (int mt = 0; mt < 4; ++mt)
                af[mt] = *(const short8*)
                    &sBuf[0][wm + mt * 16 + l16][((ks * 4 + quad) ^ (l16 & 7)) * 8];
#pragma unroll
            for (int nt = 0; nt < 4; ++nt)
                bf[nt] = *(const short8*)
                    &sBuf[1][wn + nt * 16 + l16][((ks * 4 + quad) ^ (l16 & 7)) * 8];
#pragma unroll
            for (int mt = 0; mt < 4; ++mt)
#pragma unroll
                for (int nt = 0; nt < 4; ++nt)
                    acc[mt][nt] = mfma16(af[mt], bf[nt], acc[mt][nt]);
        }
    }

    short* Cs = (short*)Cv;

    if (mode == 1) {
        // Coalesced Vt epilogue (round-8 proven).
        short* tl = &sBuf[0][0][0];
        const int b_  = r0 >> 10;
        const int p0v = r0 & 1023;
#pragma unroll 1
        for (int pass = 0; pass < 2; ++pass) {
            __syncthreads();
            if ((wave >> 1) == pass) {
#pragma unroll
                for (int nt = 0; nt < 4; ++nt) {
                    const float bv = bias[n0 + wn + nt * 16 + l16];
#pragma unroll
                    for (int mt = 0; mt < 4; ++mt) {
                        short4v pk;
#pragma unroll
                        for (int rr = 0; rr < 4; ++rr)
                            pk[rr] = f2bs(acc[mt][nt][rr] + bv);
                        *(short4v*)&tl[(nt * 16 + l16) * 132 + wm + mt * 16 +
                                       quad * 4] = pk;
                    }
                }
            }
            __syncthreads();
            const int row = tid >> 2, seg = tid & 3;
            const int n_g = n0 + pass * 64 + row;
            short* dst = Cs + ((size_t)(b_ * 768 + n_g) << 10) + p0v + seg * 32;
            const short* srcl = &tl[row * 132 + seg * 32];
#pragma unroll
            for (int u = 0; u < 4; ++u)
                *(short8*)(dst + u * 8) = *(const short8*)(srcl + u * 8);
        }
        return;
    }

    // mode 3: chunk-plane head-major
#pragma unroll
    for (int nt = 0; nt < 4; ++nt) {
        const int n = n0 + wn + nt * 16 + l16;
        const float bv = bias[n];
        const size_t hcb = (size_t)((n / 96) * 12 + ((n % 96) >> 3)) * 65536 +
                           (n % 8);
#pragma unroll
        for (int mt = 0; mt < 4; ++mt) {
#pragma unroll
            for (int rr = 0; rr < 4; ++rr) {
                const int row = r0 + wm + mt * 16 + quad * 4 + rr;
                Cs[hcb + (size_t)row * 8] = f2bs(acc[mt][nt][rr] + bv);
            }
        }
    }
}

// ---------------------------------------------------------------------------
// MFMA GEMM-BT with fp32 register-staged W (kept ONLY for O-proj, mode 2 —
// no race-safe scratch region exists for a bf16 copy of ow).
// ---------------------------------------------------------------------------
__global__ __launch_bounds__(256) void gemm_mfma(const short* __restrict__ A,
                                                 const float* __restrict__ W,
                                                 const float* __restrict__ bias,
                                                 void* __restrict__ Cv,
                                                 int mode) {
    __shared__ short sBuf[2][128][64];

    const int tid = threadIdx.x;
    const int wave = tid >> 6, lane = tid & 63;
    const int quad = lane >> 4, l16 = lane & 15;
    const int n0 = blockIdx.x * 128;
    const int r0 = blockIdx.y * 128;
    const int wm = (wave & 1) * 64;
    const int wn = (wave >> 1) * 64;

    const int lrow   = lane >> 3;
    const int lchunk = (lane & 7) ^ lrow;
    const short* Abase =
        A + (size_t)(r0 + wave * 32 + lrow) * 768 + lchunk * 8;

    const int wrow = tid >> 1;
    const int wseg = tid & 1;
    const float* Wbase = W + (size_t)(n0 + wrow) * 768 + wseg * 32;
    const int wsw = wrow & 7;

    f32x4 acc[4][4];
#pragma unroll
    for (int mt = 0; mt < 4; ++mt)
#pragma unroll
        for (int nt = 0; nt < 4; ++nt) acc[mt][nt] = (f32x4){0.f, 0.f, 0.f, 0.f};

    for (int k0 = 0; k0 < 768; k0 += 64) {
        float4 wv[8];
#pragma unroll
        for (int j = 0; j < 8; ++j)
            wv[j] = *(const float4*)(Wbase + k0 + j * 4);

        __syncthreads();

#pragma unroll
        for (int i = 0; i < 4; ++i)
            gld_lds16(Abase + k0 + (size_t)i * 8 * 768,
                      &sBuf[0][(wave * 4 + i) * 8][0]);

#pragma unroll
        for (int c = 0; c < 4; ++c) {
            const float4 a = wv[2 * c], b = wv[2 * c + 1];
            short8 p;
            p[0] = f2bs(a.x); p[1] = f2bs(a.y); p[2] = f2bs(a.z); p[3] = f2bs(a.w);
            p[4] = f2bs(b.x); p[5] = f2bs(b.y); p[6] = f2bs(b.z); p[7] = f2bs(b.w);
            *(short8*)&sBuf[1][wrow][((wseg * 4 + c) ^ wsw) * 8] = p;
        }

        __syncthreads();

#pragma unroll
        for (int ks = 0; ks < 2; ++ks) {
            short8 af[4], bf[4];
#pragma unroll
            for (int mt = 0; mt < 4; ++mt)
                af[mt] = *(const short8*)
                    &sBuf[0][wm + mt * 16 + l16][((ks * 4 + quad) ^ (l16 & 7)) * 8];
#pragma unroll
            for (int nt = 0; nt < 4; ++nt)
                bf[nt] = *(const short8*)
                    &sBuf[1][wn + nt * 16 + l16][((ks * 4 + quad) ^ (l16 & 7)) * 8];
#pragma unroll
            for (int mt = 0; mt < 4; ++mt)
#pragma unroll
                for (int nt = 0; nt < 4; ++nt)
                    acc[mt][nt] = mfma16(af[mt], bf[nt], acc[mt][nt]);
        }
    }

    float* Cf = (float*)Cv;
#pragma unroll
    for (int nt = 0; nt < 4; ++nt) {
        const int n = n0 + wn + nt * 16 + l16;
        const float bv = bias[n];
#pragma unroll
        for (int mt = 0; mt < 4; ++mt) {
#pragma unroll
            for (int rr = 0; rr < 4; ++rr) {
                const int row = r0 + wm + mt * 16 + quad * 4 + rr;
                Cf[(size_t)row * 768 + n] = acc[mt][nt][rr] + bv;
            }
        }
    }
}

// ---------------------------------------------------------------------------
// Flash attention (round-8 proven: 2-phase ping-pong pipeline, chunk-plane K,
// swizzled V, P-LDS-transpose). Grid (8h, 8mt, 8b), h on x = XCD locality.
// ---------------------------------------------------------------------------
__global__ __launch_bounds__(256) void flash_att(const short* __restrict__ QH,
                                                 const short* __restrict__ KH,
                                                 const short* __restrict__ Vt,
                                                 short* __restrict__ att,
                                                 float* __restrict__ linv) {
    __shared__ short sKp[2][12][64][8];  // 24 KB
    __shared__ short sV[2][96][8][8];    // 24 KB
    __shared__ short Pl[4][32][76];      // 19 KB

    const int h  = blockIdx.x;   // XCD selector
    const int mt = blockIdx.y;
    const int b  = blockIdx.z;
    const int tid  = threadIdx.x;
    const int wave = tid >> 6;
    const int lane = tid & 63;
    const int quad = lane >> 4;
    const int l16  = lane & 15;

    const int m0 = mt * 128 + wave * 32;
    const size_t brow = (size_t)b * 1024;
    const float scale = 0.1020620726159657f;  // 1/sqrt(96)

    short8 aq[2][3];
#pragma unroll
    for (int mf = 0; mf < 2; ++mf)
#pragma unroll
        for (int kc = 0; kc < 3; ++kc)
            aq[mf][kc] = *(const short8*)(QH +
                ((size_t)(h * 12 + kc * 4 + quad) * 8192 + brow + m0 +
                 mf * 16 + l16) * 8);

    const short* kp_[3];
#pragma unroll
    for (int i = 0; i < 3; ++i)
        kp_[i] = KH + ((size_t)(h * 12 + wave * 3 + i) * 8192 + brow + lane) * 8;

    const short* vp_[3];
#pragma unroll
    for (int i = 0; i < 3; ++i) {
        const int slot = i * 256 + tid;
        const int row = slot >> 3;
        const int g = (slot & 7) ^ (row & 7);
        vp_[i] = Vt + ((size_t)b * 768 + h * 96 + row) * 1024 + g * 8;
    }

    int vB[2];
#pragma unroll
    for (int kv = 0; kv < 2; ++kv)
        vB[kv] = l16 * 64 + (((kv * 4 + quad) ^ (l16 & 7)) * 8);

    f32x4 o[2][6];
#pragma unroll
    for (int mf = 0; mf < 2; ++mf)
#pragma unroll
        for (int nt = 0; nt < 6; ++nt) o[mf][nt] = (f32x4){0.f, 0.f, 0.f, 0.f};
    float li[2][4] = {};

#define FA_STAGE(BUF)                                                          \
    {                                                                          \
        _Pragma("unroll")                                                      \
        for (int i = 0; i < 3; ++i) {                                          \
            gld_lds16(kp_[i], &sKp[BUF][wave * 3 + i][0][0]);                  \
            kp_[i] += 512;                                                     \
        }                                                                      \
        _Pragma("unroll")                                                      \
        for (int i = 0; i < 3; ++i) {                                          \
            gld_lds16(vp_[i], (short*)sV[BUF] + (i * 256 + wave * 64) * 8);    \
            vp_[i] += 64;                                                      \
        }                                                                      \
    }

    FA_STAGE(0)
    __syncthreads();

    int cur = 0;
#pragma unroll 1
    for (int t = 0; t < 16; ++t) {
        if (t < 15) FA_STAGE(cur ^ 1)

#pragma unroll
        for (int j = 0; j < 4; ++j) {
            short8 kf[3];
#pragma unroll
            for (int kc = 0; kc < 3; ++kc)
                kf[kc] = *(const short8*)((const short*)sKp[cur] +
                    ((kc * 4 + quad) * 64 + j * 16 + l16) * 8);
            f32x4 s0 = (f32x4){0.f, 0.f, 0.f, 0.f};
            f32x4 s1 = (f32x4){0.f, 0.f, 0.f, 0.f};
            s0 = mfma16(aq[0][0], kf[0], s0);
            s1 = mfma16(aq[1][0], kf[0], s1);
            s0 = mfma16(aq[0][1], kf[1], s0);
            s1 = mfma16(aq[1][1], kf[1], s1);
            s0 = mfma16(aq[0][2], kf[2], s0);
            s1 = mfma16(aq[1][2], kf[2], s1);
#pragma unroll
            for (int r = 0; r < 4; ++r) {
                const float e0 = __expf(s0[r] * scale);
                const float e1 = __expf(s1[r] * scale);
                li[0][r] += e0;
                li[1][r] += e1;
                Pl[wave][quad * 4 + r][j * 16 + l16]      = f2bs(e0);
                Pl[wave][16 + quad * 4 + r][j * 16 + l16] = f2bs(e1);
            }
        }

        __builtin_amdgcn_s_waitcnt(0xc07f);  // lgkmcnt(0) only (vmcnt open)

        short8 ap[2][2];
#pragma unroll
        for (int mf = 0; mf < 2; ++mf)
#pragma unroll
            for (int kv = 0; kv < 2; ++kv)
                ap[mf][kv] = *(const short8*)
                    &Pl[wave][mf * 16 + l16][kv * 32 + quad * 8];

#pragma unroll
        for (int nt = 0; nt < 6; ++nt) {
#pragma unroll
            for (int kv = 0; kv < 2; ++kv) {
                const short8 v =
                    *(const short8*)((const short*)sV[cur] + nt * 1024 + vB[kv]);
                o[0][nt] = mfma16(ap[0][kv], v, o[0][nt]);
                o[1][nt] = mfma16(ap[1][kv], v, o[1][nt]);
            }
        }

        __syncthreads();
        cur ^= 1;
    }
#undef FA_STAGE

#pragma unroll
    for (int mf = 0; mf < 2; ++mf) {
        float inv[4];
#pragma unroll
        for (int r = 0; r < 4; ++r) {
#pragma unroll
            for (int off = 1; off < 16; off <<= 1)
                li[mf][r] += __shfl_xor(li[mf][r], off, 16);
            inv[r] = 1.0f / li[mf][r];
        }
#pragma unroll
        for (int nt = 0; nt < 6; ++nt)
#pragma unroll
            for (int r = 0; r < 4; ++r)
                att[(brow + m0 + mf * 16 + quad * 4 + r) * 768 + h * 96 +
                    nt * 16 + l16] = f2bs(o[mf][nt][r] * inv[r]);
        if (l16 == 0) {
#pragma unroll
            for (int r = 0; r < 4; ++r)
                linv[(((size_t)b * 8 + h) << 10) + m0 + mf * 16 + quad * 4 + r] =
                    inv[r];
        }
    }
}

// ---------------------------------------------------------------------------
// Head-averaged attention map (round-7 proven: chunk-plane contiguous DMA).
// ---------------------------------------------------------------------------
__global__ __launch_bounds__(256) void attn_avg6(const short* __restrict__ QH,
                                                 const short* __restrict__ KH,
                                                 const float* __restrict__ linv,
                                                 float* __restrict__ avg) {
    __shared__ short sQ[12][128][8];  // 24 KB
    __shared__ short sK[12][128][8];  // 24 KB

    const int pt = blockIdx.x;
    const int mt = blockIdx.y;
    const int b  = blockIdx.z;
    const int tid  = threadIdx.x;
    const int wave = tid >> 6;
    const int lane = tid & 63;
    const int quad = lane >> 4;
    const int l16  = lane & 15;

    const int m0 = mt * 128;
    const int p0 = pt * 128;
    const size_t brow = (size_t)b * 1024;
    const int wm = (wave & 1) * 64;
    const int wn = (wave >> 1) * 64;
    const float scale2 = 0.14724445f;  // (1/sqrt(96)) * log2(e)

    const size_t qoff = (size_t)(brow + m0 + lane) * 8;
    const size_t koff = (size_t)(brow + p0 + lane) * 8;
    const float* Lb_  = linv + (((size_t)b * 8) << 10) + m0 + wm + quad * 4;

    f32x4 acc[4][4];
#pragma unroll
    for (int x = 0; x < 4; ++x)
#pragma unroll
        for (int y = 0; y < 4; ++y) acc[x][y] = (f32x4){0.f, 0.f, 0.f, 0.f};

#pragma unroll 1
    for (int h = 0; h < 8; ++h) {
        __syncthreads();

#pragma unroll
        for (int i = 0; i < 6; ++i) {
            const int j = wave * 6 + i;
            const int c = j >> 1, half = j & 1;
            const size_t pl = (size_t)(h * 12 + c) * 65536 + half * 512;
            gld_lds16(QH + pl + qoff, &sQ[c][half * 64][0]);
            gld_lds16(KH + pl + koff, &sK[c][half * 64][0]);
        }

        f32x4 il[4];
#pragma unroll
        for (int x = 0; x < 4; ++x)
            il[x] = 0.125f * *(const f32x4*)(Lb_ + ((size_t)h << 10) + x * 16);

        __syncthreads();

        short8 af[4][3], bf[4][3];
#pragma unroll
        for (int x = 0; x < 4; ++x)
#pragma unroll
            for (int kc = 0; kc < 3; ++kc) {
                af[x][kc] = *(const short8*)&sQ[kc * 4 + quad][wm + x * 16 + l16][0];
                bf[x][kc] = *(const short8*)&sK[kc * 4 + quad][wn + x * 16 + l16][0];
            }

#pragma unroll
        for (int x = 0; x < 4; ++x)
#pragma unroll
            for (int y = 0; y < 4; ++y) {
                f32x4 s = (f32x4){0.f, 0.f, 0.f, 0.f};
                s = mfma16(af[x][0], bf[y][0], s);
                s = mfma16(af[x][1], bf[y][1], s);
                s = mfma16(af[x][2], bf[y][2], s);
#pragma unroll
                for (int r = 0; r < 4; ++r)
                    acc[x][y][r] += __builtin_exp2f(s[r] * scale2) * il[x][r];
            }
    }

#pragma unroll
    for (int x = 0; x < 4; ++x)
#pragma unroll
        for (int y = 0; y < 4; ++y)
#pragma unroll
            for (int r = 0; r < 4; ++r)
                avg[(brow + m0 + wm + x * 16 + quad * 4 + r) * 1024 +
                    p0 + wn + y * 16 + l16] = acc[x][y][r];
}

extern "C" void kernel_launch(void* const* d_in, const int* in_sizes, int n_in,
                              void* d_out, int out_size, void* d_ws, size_t ws_size,
                              hipStream_t stream) {
    (void)in_sizes; (void)n_in; (void)out_size; (void)d_ws; (void)ws_size;

    float* mam = (float*)d_in[0];
    float* pat = (float*)d_in[1];
    const float* qw = (const float*)d_in[2];
    const float* qb = (const float*)d_in[3];
    const float* kw = (const float*)d_in[4];
    const float* kb = (const float*)d_in[5];
    const float* vw = (const float*)d_in[6];
    const float* vb = (const float*)d_in[7];
    const float* ow = (const float*)d_in[8];
    const float* ob = (const float*)d_in[9];

    const size_t NTOK = (size_t)8 * 1024 * 768;
    const size_t NW   = (size_t)768 * 768;
    float* out_att = (float*)d_out;
    float* out_avg = out_att + NTOK;

    short* Am = (short*)d_out;           // bf16 mammo  @ out_att head (dead after Q-proj)
    short* Ap = (short*)out_avg;         // bf16 patho  @ out_avg head (dead after V-proj)
    short* Qh = (short*)mam;             // bf16 Q chunk-plane @ mammo[0:NTOK]
    short* Kh = Qh + NTOK;               // bf16 K chunk-plane @ mammo[NTOK:2*NTOK]
    short* Vt = (short*)pat;             // bf16 Vt     @ patho[0:NTOK]
    short* Ab = Vt + NTOK;               // bf16 att    @ patho[NTOK:2*NTOK]
    float* LV = (float*)(Am + NTOK);     // 1/l (256KB) @ out_att tail (dead before O-proj)
    // bf16 weights after LV in out_att tail: live only until V-proj; region is
    // first overwritten by O-proj (which doesn't read them). 16.4MB < 25.2MB cap.
    short* WQ = (short*)(LV + 65536);
    short* WK = WQ + NW;
    short* WV = WK + NW;

    dim3 bb(256), gg(6, 64);
    cvt_b16<<<3072, bb, 0, stream>>>(mam, Am);
    cvt_b16<<<3072, bb, 0, stream>>>(pat, Ap);
    cvt_b16<<<288, bb, 0, stream>>>(qw, WQ);
    cvt_b16<<<288, bb, 0, stream>>>(kw, WK);
    cvt_b16<<<288, bb, 0, stream>>>(vw, WV);

    gemm_bw<<<gg, bb, 0, stream>>>(Am, WQ, qb, Qh, 3);
    gemm_bw<<<gg, bb, 0, stream>>>(Ap, WK, kb, Kh, 3);
    gemm_bw<<<gg, bb, 0, stream>>>(Ap, WV, vb, Vt, 1);

    flash_att<<<dim3(8, 8, 8), bb, 0, stream>>>(Qh, Kh, Vt, Ab, LV);
    attn_avg6<<<dim3(8, 8, 8), bb, 0, stream>>>(Qh, Kh, LV, out_avg);

    gemm_mfma<<<gg, bb, 0, stream>>>(Ab, ow, ob, out_att, 2);
}

// Round 11
// 282.075 us; speedup vs baseline: 1.8287x; 1.0450x over previous
//
#include <hip/hip_runtime.h>

typedef short short4v __attribute__((ext_vector_type(4)));
typedef short short8 __attribute__((ext_vector_type(8)));
typedef float f32x4 __attribute__((ext_vector_type(4)));

__device__ __forceinline__ f32x4 mfma16(short8 a, short8 b, f32x4 c) {
    return __builtin_amdgcn_mfma_f32_16x16x32_bf16(a, b, c, 0, 0, 0);
}
__device__ __forceinline__ short f2bs(float f) {
    __bf16 h = (__bf16)f;
    return __builtin_bit_cast(short, h);
}
__device__ __forceinline__ void gld_lds16(const void* g, void* l) {
    __builtin_amdgcn_global_load_lds(
        (const __attribute__((address_space(1))) void*)g,
        (__attribute__((address_space(3))) void*)l, 16, 0, 0);
}

// ---------------------------------------------------------------------------
// fp32 -> bf16 bulk convert (8 elems/thread)
// ---------------------------------------------------------------------------
__global__ __launch_bounds__(256) void cvt_b16(const float* __restrict__ in,
                                               short* __restrict__ out) {
    const size_t i = ((size_t)blockIdx.x * 256 + threadIdx.x) * 8;
    const float4 v0 = *(const float4*)(in + i);
    const float4 v1 = *(const float4*)(in + i + 4);
    short8 s;
    s[0] = f2bs(v0.x); s[1] = f2bs(v0.y); s[2] = f2bs(v0.z); s[3] = f2bs(v0.w);
    s[4] = f2bs(v1.x); s[5] = f2bs(v1.y); s[6] = f2bs(v1.z); s[7] = f2bs(v1.w);
    *(short8*)(out + i) = s;
}

// ---------------------------------------------------------------------------
// gemm_bw: BOTH A and W bf16, BOTH staged via global_load_lds (m97 2-barrier
// shape: per K-step 8 DMA + 16 ds_read_b128 + 32 MFMA, zero staging VALU).
// mode 1: C bf16 Vt[b][768][1024] via LDS-transposed coalesced epilogue;
// mode 2: C fp32 row-major (O-proj);
// mode 3: C bf16 chunk-plane head-major QH[h][c][t][8].
// ---------------------------------------------------------------------------
__global__ __launch_bounds__(256) void gemm_bw(const short* __restrict__ A,
                                               const short* __restrict__ Wb,
                                               const float* __restrict__ bias,
                                               void* __restrict__ Cv,
                                               int mode) {
    __shared__ short sBuf[2][128][64];

    const int tid = threadIdx.x;
    const int wave = tid >> 6, lane = tid & 63;
    const int quad = lane >> 4, l16 = lane & 15;
    const int n0 = blockIdx.x * 128;
    const int r0 = blockIdx.y * 128;
    const int wm = (wave & 1) * 64;
    const int wn = (wave >> 1) * 64;

    const int lrow   = lane >> 3;
    const int lchunk = (lane & 7) ^ lrow;
    const short* Abase =
        A + (size_t)(r0 + wave * 32 + lrow) * 768 + lchunk * 8;
    const short* Wbase =
        Wb + (size_t)(n0 + wave * 32 + lrow) * 768 + lchunk * 8;

    f32x4 acc[4][4];
#pragma unroll
    for (int mt = 0; mt < 4; ++mt)
#pragma unroll
        for (int nt = 0; nt < 4; ++nt) acc[mt][nt] = (f32x4){0.f, 0.f, 0.f, 0.f};

    for (int k0 = 0; k0 < 768; k0 += 64) {
        __syncthreads();  // all waves done reading previous tile

#pragma unroll
        for (int i = 0; i < 4; ++i) {
            gld_lds16(Abase + k0 + (size_t)i * 8 * 768,
                      &sBuf[0][(wave * 4 + i) * 8][0]);
            gld_lds16(Wbase + k0 + (size_t)i * 8 * 768,
                      &sBuf[1][(wave * 4 + i) * 8][0]);
        }

        __syncthreads();  // vmcnt drain: tiles ready

#pragma unroll
        for (int ks = 0; ks < 2; ++ks) {
            short8 af[4], bf[4];
#pragma unroll
            for (int mt = 0; mt < 4; ++mt)
                af[mt] = *(const short8*)
                    &sBuf[0][wm + mt * 16 + l16][((ks * 4 + quad) ^ (l16 & 7)) * 8];
#pragma unroll
            for (int nt = 0; nt < 4; ++nt)
                bf[nt] = *(const short8*)
                    &sBuf[1][wn + nt * 16 + l16][((ks * 4 + quad) ^ (l16 & 7)) * 8];
#pragma unroll
            for (int mt = 0; mt < 4; ++mt)
#pragma unroll
                for (int nt = 0; nt < 4; ++nt)
                    acc[mt][nt] = mfma16(af[mt], bf[nt], acc[mt][nt]);
        }
    }

    short* Cs = (short*)Cv;

    if (mode == 1) {
        // Coalesced Vt epilogue (round-8 proven).
        short* tl = &sBuf[0][0][0];
        const int b_  = r0 >> 10;
        const int p0v = r0 & 1023;
#pragma unroll 1
        for (int pass = 0; pass < 2; ++pass) {
            __syncthreads();
            if ((wave >> 1) == pass) {
#pragma unroll
                for (int nt = 0; nt < 4; ++nt) {
                    const float bv = bias[n0 + wn + nt * 16 + l16];
#pragma unroll
                    for (int mt = 0; mt < 4; ++mt) {
                        short4v pk;
#pragma unroll
                        for (int rr = 0; rr < 4; ++rr)
                            pk[rr] = f2bs(acc[mt][nt][rr] + bv);
                        *(short4v*)&tl[(nt * 16 + l16) * 132 + wm + mt * 16 +
                                       quad * 4] = pk;
                    }
                }
            }
            __syncthreads();
            const int row = tid >> 2, seg = tid & 3;
            const int n_g = n0 + pass * 64 + row;
            short* dst = Cs + ((size_t)(b_ * 768 + n_g) << 10) + p0v + seg * 32;
            const short* srcl = &tl[row * 132 + seg * 32];
#pragma unroll
            for (int u = 0; u < 4; ++u)
                *(short8*)(dst + u * 8) = *(const short8*)(srcl + u * 8);
        }
        return;
    }

    if (mode == 2) {
        float* Cf = (float*)Cv;
#pragma unroll
        for (int nt = 0; nt < 4; ++nt) {
            const int n = n0 + wn + nt * 16 + l16;
            const float bv = bias[n];
#pragma unroll
            for (int mt = 0; mt < 4; ++mt) {
#pragma unroll
                for (int rr = 0; rr < 4; ++rr) {
                    const int row = r0 + wm + mt * 16 + quad * 4 + rr;
                    Cf[(size_t)row * 768 + n] = acc[mt][nt][rr] + bv;
                }
            }
        }
        return;
    }

    // mode 3: chunk-plane head-major
#pragma unroll
    for (int nt = 0; nt < 4; ++nt) {
        const int n = n0 + wn + nt * 16 + l16;
        const float bv = bias[n];
        const size_t hcb = (size_t)((n / 96) * 12 + ((n % 96) >> 3)) * 65536 +
                           (n % 8);
#pragma unroll
        for (int mt = 0; mt < 4; ++mt) {
#pragma unroll
            for (int rr = 0; rr < 4; ++rr) {
                const int row = r0 + wm + mt * 16 + quad * 4 + rr;
                Cs[hcb + (size_t)row * 8] = f2bs(acc[mt][nt][rr] + bv);
            }
        }
    }
}

// ---------------------------------------------------------------------------
// Flash attention (round-8 proven: 2-phase ping-pong pipeline, chunk-plane K,
// swizzled V, P-LDS-transpose). Grid (8h, 8mt, 8b), h on x = XCD locality.
// ---------------------------------------------------------------------------
__global__ __launch_bounds__(256) void flash_att(const short* __restrict__ QH,
                                                 const short* __restrict__ KH,
                                                 const short* __restrict__ Vt,
                                                 short* __restrict__ att,
                                                 float* __restrict__ linv) {
    __shared__ short sKp[2][12][64][8];  // 24 KB
    __shared__ short sV[2][96][8][8];    // 24 KB
    __shared__ short Pl[4][32][76];      // 19 KB

    const int h  = blockIdx.x;   // XCD selector
    const int mt = blockIdx.y;
    const int b  = blockIdx.z;
    const int tid  = threadIdx.x;
    const int wave = tid >> 6;
    const int lane = tid & 63;
    const int quad = lane >> 4;
    const int l16  = lane & 15;

    const int m0 = mt * 128 + wave * 32;
    const size_t brow = (size_t)b * 1024;
    const float scale = 0.1020620726159657f;  // 1/sqrt(96)

    short8 aq[2][3];
#pragma unroll
    for (int mf = 0; mf < 2; ++mf)
#pragma unroll
        for (int kc = 0; kc < 3; ++kc)
            aq[mf][kc] = *(const short8*)(QH +
                ((size_t)(h * 12 + kc * 4 + quad) * 8192 + brow + m0 +
                 mf * 16 + l16) * 8);

    const short* kp_[3];
#pragma unroll
    for (int i = 0; i < 3; ++i)
        kp_[i] = KH + ((size_t)(h * 12 + wave * 3 + i) * 8192 + brow + lane) * 8;

    const short* vp_[3];
#pragma unroll
    for (int i = 0; i < 3; ++i) {
        const int slot = i * 256 + tid;
        const int row = slot >> 3;
        const int g = (slot & 7) ^ (row & 7);
        vp_[i] = Vt + ((size_t)b * 768 + h * 96 + row) * 1024 + g * 8;
    }

    int vB[2];
#pragma unroll
    for (int kv = 0; kv < 2; ++kv)
        vB[kv] = l16 * 64 + (((kv * 4 + quad) ^ (l16 & 7)) * 8);

    f32x4 o[2][6];
#pragma unroll
    for (int mf = 0; mf < 2; ++mf)
#pragma unroll
        for (int nt = 0; nt < 6; ++nt) o[mf][nt] = (f32x4){0.f, 0.f, 0.f, 0.f};
    float li[2][4] = {};

#define FA_STAGE(BUF)                                                          \
    {                                                                          \
        _Pragma("unroll")                                                      \
        for (int i = 0; i < 3; ++i) {                                          \
            gld_lds16(kp_[i], &sKp[BUF][wave * 3 + i][0][0]);                  \
            kp_[i] += 512;                                                     \
        }                                                                      \
        _Pragma("unroll")                                                      \
        for (int i = 0; i < 3; ++i) {                                          \
            gld_lds16(vp_[i], (short*)sV[BUF] + (i * 256 + wave * 64) * 8);    \
            vp_[i] += 64;                                                      \
        }                                                                      \
    }

    FA_STAGE(0)
    __syncthreads();

    int cur = 0;
#pragma unroll 1
    for (int t = 0; t < 16; ++t) {
        if (t < 15) FA_STAGE(cur ^ 1)

#pragma unroll
        for (int j = 0; j < 4; ++j) {
            short8 kf[3];
#pragma unroll
            for (int kc = 0; kc < 3; ++kc)
                kf[kc] = *(const short8*)((const short*)sKp[cur] +
                    ((kc * 4 + quad) * 64 + j * 16 + l16) * 8);
            f32x4 s0 = (f32x4){0.f, 0.f, 0.f, 0.f};
            f32x4 s1 = (f32x4){0.f, 0.f, 0.f, 0.f};
            s0 = mfma16(aq[0][0], kf[0], s0);
            s1 = mfma16(aq[1][0], kf[0], s1);
            s0 = mfma16(aq[0][1], kf[1], s0);
            s1 = mfma16(aq[1][1], kf[1], s1);
            s0 = mfma16(aq[0][2], kf[2], s0);
            s1 = mfma16(aq[1][2], kf[2], s1);
#pragma unroll
            for (int r = 0; r < 4; ++r) {
                const float e0 = __expf(s0[r] * scale);
                const float e1 = __expf(s1[r] * scale);
                li[0][r] += e0;
                li[1][r] += e1;
                Pl[wave][quad * 4 + r][j * 16 + l16]      = f2bs(e0);
                Pl[wave][16 + quad * 4 + r][j * 16 + l16] = f2bs(e1);
            }
        }

        __builtin_amdgcn_s_waitcnt(0xc07f);  // lgkmcnt(0) only (vmcnt open)

        short8 ap[2][2];
#pragma unroll
        for (int mf = 0; mf < 2; ++mf)
#pragma unroll
            for (int kv = 0; kv < 2; ++kv)
                ap[mf][kv] = *(const short8*)
                    &Pl[wave][mf * 16 + l16][kv * 32 + quad * 8];

#pragma unroll
        for (int nt = 0; nt < 6; ++nt) {
#pragma unroll
            for (int kv = 0; kv < 2; ++kv) {
                const short8 v =
                    *(const short8*)((const short*)sV[cur] + nt * 1024 + vB[kv]);
                o[0][nt] = mfma16(ap[0][kv], v, o[0][nt]);
                o[1][nt] = mfma16(ap[1][kv], v, o[1][nt]);
            }
        }

        __syncthreads();
        cur ^= 1;
    }
#undef FA_STAGE

#pragma unroll
    for (int mf = 0; mf < 2; ++mf) {
        float inv[4];
#pragma unroll
        for (int r = 0; r < 4; ++r) {
#pragma unroll
            for (int off = 1; off < 16; off <<= 1)
                li[mf][r] += __shfl_xor(li[mf][r], off, 16);
            inv[r] = 1.0f / li[mf][r];
        }
#pragma unroll
        for (int nt = 0; nt < 6; ++nt)
#pragma unroll
            for (int r = 0; r < 4; ++r)
                att[(brow + m0 + mf * 16 + quad * 4 + r) * 768 + h * 96 +
                    nt * 16 + l16] = f2bs(o[mf][nt][r] * inv[r]);
        if (l16 == 0) {
#pragma unroll
            for (int r = 0; r < 4; ++r)
                linv[(((size_t)b * 8 + h) << 10) + m0 + mf * 16 + quad * 4 + r] =
                    inv[r];
        }
    }
}

// ---------------------------------------------------------------------------
// Head-averaged attention map, round-10: 2-phase pipelined version of the
// proven attn_avg6. Each h's 12 chunk-planes split into 3 sub-steps of 4
// planes; global chunk index per sub-step t is 4t+plane (linear walk), so
// DMA pointers advance by a constant 4*65536 shorts. Ping-pong buffers
// sT[2][2][4][128][8] (32 KB): stage sub-step t+1 while computing t; one
// barrier per sub-step. QK s-accumulator persists across the 3 sub-steps,
// exp-folds at kc==2 (identical math/order to attn_avg6). Read pattern per
// sub-step is byte-identical to attn_avg6's (measured 0 bank conflicts).
// Grid (8 pt, 8 mt, 8 b) = 512 blocks, 4 waves, each wave 64m x 64p.
// ---------------------------------------------------------------------------
__global__ __launch_bounds__(256) void attn_avg7(const short* __restrict__ QH,
                                                 const short* __restrict__ KH,
                                                 const float* __restrict__ linv,
                                                 float* __restrict__ avg) {
    __shared__ short sT[2][2][4][128][8];  // [buf][tensor][plane][row][8] 32 KB

    const int pt = blockIdx.x;
    const int mt = blockIdx.y;
    const int b  = blockIdx.z;
    const int tid  = threadIdx.x;
    const int wave = tid >> 6;
    const int lane = tid & 63;
    const int quad = lane >> 4;
    const int l16  = lane & 15;

    const int m0 = mt * 128;
    const int p0 = pt * 128;
    const size_t brow = (size_t)b * 1024;
    const int wm = (wave & 1) * 64;
    const int wn = (wave >> 1) * 64;
    const float scale2 = 0.14724445f;  // (1/sqrt(96)) * log2(e)

    // per-thread DMA roles: wave>>1 = tensor (0 Q, 1 K);
    // instr i: plane = (wave&1)*2 + (i>>1), half = i&1.
    const int tensor = wave >> 1;
    const short* srcp[4];
    int dsto[4];
#pragma unroll
    for (int i = 0; i < 4; ++i) {
        const int plane = (wave & 1) * 2 + (i >> 1);
        const int half  = i & 1;
        const short* base = tensor ? KH : QH;
        const int r0_ = tensor ? p0 : m0;
        srcp[i] = base + ((size_t)plane * 8192 + brow + r0_ + half * 64 + lane) * 8;
        dsto[i] = ((tensor * 4 + plane) * 128 + half * 64) * 8;  // within one buf
    }

    const float* Lb_ = linv + (((size_t)b * 8) << 10) + m0 + wm + quad * 4;

    f32x4 acc[4][4];
#pragma unroll
    for (int x = 0; x < 4; ++x)
#pragma unroll
        for (int y = 0; y < 4; ++y) acc[x][y] = (f32x4){0.f, 0.f, 0.f, 0.f};

#define AV_STAGE(BUF)                                                          \
    {                                                                          \
        short* bb_ = (short*)sT + (BUF) * 8192;                                \
        _Pragma("unroll")                                                      \
        for (int i = 0; i < 4; ++i) {                                          \
            gld_lds16(srcp[i], bb_ + dsto[i]);                                 \
            srcp[i] += 262144; /* 4 planes * 65536 shorts */                   \
        }                                                                      \
    }

    AV_STAGE(0)
    __syncthreads();

    int cur = 0;
#pragma unroll 1
    for (int h = 0; h < 8; ++h) {
        f32x4 il[4];
#pragma unroll
        for (int x = 0; x < 4; ++x)
            il[x] = 0.125f * *(const f32x4*)(Lb_ + ((size_t)h << 10) + x * 16);

        f32x4 s[4][4];
#pragma unroll
        for (int x = 0; x < 4; ++x)
#pragma unroll
            for (int y = 0; y < 4; ++y) s[x][y] = (f32x4){0.f, 0.f, 0.f, 0.f};

#pragma unroll
        for (int kc = 0; kc < 3; ++kc) {
            if (kc != 2 || h != 7) AV_STAGE(cur ^ 1)

            const short* qb = (const short*)sT + cur * 8192 + quad * 1024;
            const short* kb = qb + 4096;
            short8 af[4], bf[4];
#pragma unroll
            for (int x = 0; x < 4; ++x)
                af[x] = *(const short8*)(qb + (wm + x * 16 + l16) * 8);
#pragma unroll
            for (int y = 0; y < 4; ++y)
                bf[y] = *(const short8*)(kb + (wn + y * 16 + l16) * 8);
#pragma unroll
            for (int x = 0; x < 4; ++x)
#pragma unroll
                for (int y = 0; y < 4; ++y)
                    s[x][y] = mfma16(af[x], bf[y], s[x][y]);

            if (kc == 2) {
#pragma unroll
                for (int x = 0; x < 4; ++x)
#pragma unroll
                    for (int y = 0; y < 4; ++y)
#pragma unroll
                        for (int r = 0; r < 4; ++r)
                            acc[x][y][r] +=
                                __builtin_exp2f(s[x][y][r] * scale2) * il[x][r];
            }

            __syncthreads();
            cur ^= 1;
        }
    }
#undef AV_STAGE

#pragma unroll
    for (int x = 0; x < 4; ++x)
#pragma unroll
        for (int y = 0; y < 4; ++y)
#pragma unroll
            for (int r = 0; r < 4; ++r)
                avg[(brow + m0 + wm + x * 16 + quad * 4 + r) * 1024 +
                    p0 + wn + y * 16 + l16] = acc[x][y][r];
}

extern "C" void kernel_launch(void* const* d_in, const int* in_sizes, int n_in,
                              void* d_out, int out_size, void* d_ws, size_t ws_size,
                              hipStream_t stream) {
    (void)in_sizes; (void)n_in; (void)out_size; (void)d_ws; (void)ws_size;

    float* mam = (float*)d_in[0];
    float* pat = (float*)d_in[1];
    const float* qw = (const float*)d_in[2];
    const float* qb = (const float*)d_in[3];
    const float* kw = (const float*)d_in[4];
    const float* kb = (const float*)d_in[5];
    const float* vw = (const float*)d_in[6];
    const float* vb = (const float*)d_in[7];
    const float* ow = (const float*)d_in[8];
    const float* ob = (const float*)d_in[9];

    const size_t NTOK = (size_t)8 * 1024 * 768;
    const size_t NW   = (size_t)768 * 768;
    float* out_att = (float*)d_out;
    float* out_avg = out_att + NTOK;

    short* Am = (short*)d_out;           // bf16 mammo  @ out_att head (dead after Q-proj)
    short* Ap = (short*)out_avg;         // bf16 patho  @ out_avg head (dead after V-proj)
    short* Qh = (short*)mam;             // bf16 Q chunk-plane @ mammo[0:NTOK]
    short* Kh = Qh + NTOK;               // bf16 K chunk-plane @ mammo[NTOK:2*NTOK]
    short* Vt = (short*)pat;             // bf16 Vt     @ patho[0:NTOK]
    short* Ab = Vt + NTOK;               // bf16 att    @ patho[NTOK:2*NTOK]
    float* LV = (float*)(Am + NTOK);     // 1/l (256KB) @ out_att tail (dead before O-proj)
    // bf16 q/k/v weights after LV in out_att tail: live only until V-proj;
    // region first overwritten by O-proj (which doesn't read them).
    short* WQ = (short*)(LV + 65536);
    short* WK = WQ + NW;
    short* WV = WK + NW;
    // bf16 o weights: reuse Qh region (mam head) — Qh is dead after attn_avg7,
    // and the cvt is enqueued after attn_avg7 (stream-serial => race-free).
    short* WO = Qh;

    dim3 bb(256), gg(6, 64);
    cvt_b16<<<3072, bb, 0, stream>>>(mam, Am);
    cvt_b16<<<3072, bb, 0, stream>>>(pat, Ap);
    cvt_b16<<<288, bb, 0, stream>>>(qw, WQ);
    cvt_b16<<<288, bb, 0, stream>>>(kw, WK);
    cvt_b16<<<288, bb, 0, stream>>>(vw, WV);

    gemm_bw<<<gg, bb, 0, stream>>>(Am, WQ, qb, Qh, 3);
    gemm_bw<<<gg, bb, 0, stream>>>(Ap, WK, kb, Kh, 3);
    gemm_bw<<<gg, bb, 0, stream>>>(Ap, WV, vb, Vt, 1);

    flash_att<<<dim3(8, 8, 8), bb, 0, stream>>>(Qh, Kh, Vt, Ab, LV);
    attn_avg7<<<dim3(8, 8, 8), bb, 0, stream>>>(Qh, Kh, LV, out_avg);

    cvt_b16<<<288, bb, 0, stream>>>(ow, WO);
    gemm_bw<<<gg, bb, 0, stream>>>(Ab, WO, ob, out_att, 2);
}